// Round 4
// baseline (367.990 us; speedup 1.0000x reference)
//
#include <hip/hip_runtime.h>

#define T_ 32
#define B_ 32
#define MAPD 517
#define P_ 256
#define FLATD (MAPD*P_)   // 132352
#define TBN (T_*B_)       // 1024

typedef unsigned short u16;
typedef unsigned int u32;
typedef __attribute__((ext_vector_type(4))) short short4v;
typedef __attribute__((ext_vector_type(8))) short short8v;
typedef __attribute__((ext_vector_type(4))) float f32x4;
typedef __attribute__((ext_vector_type(2))) float f32x2;
typedef __attribute__((ext_vector_type(4))) u32 u32x4;

__device__ __forceinline__ float bfv(u16 u){ u32 x = ((u32)u)<<16; return __uint_as_float(x); }
__device__ __forceinline__ u16 fbf(float f){
  u32 x = __float_as_uint(f);
  return (u16)((x + 0x7fffu + ((x>>16)&1u))>>16);
}
template<bool F32> __device__ __forceinline__ float ld(const void* p, size_t i){
  if constexpr (F32) return ((const float*)p)[i];
  else               return bfv(((const u16*)p)[i]);
}

// ---- dtype probe: 1 if float inputs are fp32, 0 if bf16 ----
__global__ void k_probe(const void* img, int* flag){
  if (threadIdx.x == 0 && blockIdx.x == 0){
    const u16* u = (const u16*)img;
    int cnt = 0;
    for (int i = 0; i < 256; ++i) if (u[i] <= 0x4380u) ++cnt;
    *flag = (cnt < 240) ? 1 : 0;
  }
}

// ---- K-prep (fused): conv frag layouts + FWF (fc MFMA B-frags) + ST0T transpose ----
__global__ __launch_bounds__(256) void k_prep(const void* c1w, const void* c2w, const void* c3w,
                                              const void* fcw, const void* st0,
                                              u16* W1F, u16* W2F, u16* W3F, u16* FWF, u16* ST0T,
                                              const int* flag){
  __shared__ __align__(16) char smem_[32768];
  bool f32 = (*flag != 0);
  int bid = blockIdx.x, tid = threadIdx.x;
  if (bid < 24){
    int idx = bid*256 + tid;                   // 6144
    int j = idx & 7, l = (idx>>3) & 63, t = idx>>9;
    int nt = t/6, s = t - nt*6;
    int oc = nt*16 + (l&15);
    int kk = 8*(4*s + (l>>4)) + j;
    float v = f32 ? ((const float*)c1w)[oc*192+kk] : bfv(((const u16*)c1w)[oc*192+kk]);
    W1F[idx] = fbf(v);
  } else if (bid < 152){
    int idx = (bid-24)*256 + tid;              // 32768
    int j = idx & 7, l = (idx>>3) & 63, s = (idx>>9) & 15, nt = idx>>13;
    int oc = nt*16 + (l&15);
    int cin = (l>>4)*8 + j;
    int src = oc*512 + cin*16 + (s>>2)*4 + (s&3);
    float v = f32 ? ((const float*)c2w)[src] : bfv(((const u16*)c2w)[src]);
    W2F[idx] = fbf(v);
  } else if (bid < 296){
    int idx = (bid-152)*256 + tid;             // 36864
    int j = idx & 7, l = (idx>>3) & 63, t = idx>>9;   // t = nt*18+s
    int nt = t/18, s = t - nt*18;
    int oc = nt*16 + (l&15);
    int c = (s&1)*32 + (l>>4)*8 + j;
    int src = oc*576 + c*9 + (s>>1);
    float v = f32 ? ((const float*)c3w)[src] : bfv(((const u16*)c3w)[src]);
    W3F[idx] = fbf(v);
  } else if (bid < 424){
    // FWF: MFMA B-fragments of fc_w for k_fc.
    int b = bid - 296;                          // 128 blocks x 4096 elems
    for (int it = 0; it < 16; ++it){
      int idx = (b*16 + it)*256 + tid;          // 524288 total
      int j = idx & 7, l = (idx>>3) & 63, frag = idx >> 9;
      int nt = frag >> 5, kt = frag & 31;
      int kc = kt*32 + ((l>>4)<<3) + j;
      int kr = (kc & 63)*16 + (kc >> 6);
      int o  = nt*16 + (l & 15);
      float v = f32 ? ((const float*)fcw)[(size_t)o*1024 + kr]
                    : bfv(((const u16*)fcw)[(size_t)o*1024 + kr]);
      FWF[idx] = fbf(v);
    }
  } else {
    // ST0T[p][c][b] transpose
    u16* tile = (u16*)smem_;                   // 32,768 B
    int b0 = bid - 424;                        // 260 blocks
    int c0 = (b0 >> 2)*8, p0 = (b0 & 3)*64;
    for (int it = 0; it < 64; ++it){
      int idx = it*256 + tid;
      int pl = idx & 63, b = (idx>>6)&31, ci = idx>>11;
      int c = c0 + ci;
      float v = 0.f;
      if (c < MAPD)
        v = f32 ? ((const float*)st0)[((size_t)b*MAPD+c)*256 + p0+pl]
                : bfv(((const u16*)st0)[((size_t)b*MAPD+c)*256 + p0+pl]);
      tile[ci*2048 + pl*32 + b] = fbf(v);
    }
    __syncthreads();
    for (int it = 0; it < 64; ++it){
      int idx = it*256 + tid;
      int b = idx & 31, ci = (idx>>5)&7, pl = idx>>8;
      int c = c0 + ci;
      if (c < MAPD)
        ST0T[((size_t)(p0+pl)*MAPD + c)*32 + b] = tile[ci*2048 + pl*32 + b];
    }
  }
}

// ---- K-meta (fused): prev-writer/coef + one-hot into H ; last-writer/coef ----
__global__ void k_meta(const int* pos, const void* done, const int* lact,
                       int* prev, float* coef, float* H, int* lastw, float* lastc, const int* flag){
  bool f32 = (*flag != 0);
  int bid = blockIdx.x;
  if (bid < 4){
    int i = bid*256 + threadIdx.x;
    int t = i >> 5, b = i & 31;
    int p = pos[i*2]*16 + pos[i*2+1];
    int pv = -1;
    for (int s = t-1; s >= 0; --s){
      int n = s*32 + b;
      if (pos[n*2]*16 + pos[n*2+1] == p){ pv = s; break; }
    }
    float cf = 1.f;
    for (int s = (pv<0?0:pv+1); s <= t-1; ++s)
      cf *= (1.f - (f32 ? ((const float*)done)[s*32+b] : bfv(((const u16*)done)[s*32+b])));
    prev[i] = pv; coef[i] = cf;
    int la = lact[i];
    #pragma unroll
    for (int a = 0; a < 5; ++a) H[(size_t)i*MAPD + 512 + a] = (la == a) ? 1.f : 0.f;
  } else {
    int i = (bid-4)*256 + threadIdx.x;
    int b = i >> 8, p = i & 255;
    int lw = -1;
    for (int s = T_-1; s >= 0; --s){
      int n = s*32 + b;
      if (pos[n*2]*16 + pos[n*2+1] == p){ lw = s; break; }
    }
    float cf = 1.f;
    for (int s = (lw<0?0:lw+1); s < T_; ++s)
      cf *= (1.f - (f32 ? ((const float*)done)[s*32+b] : bfv(((const u16*)done)[s*32+b])));
    lastw[i] = lw; lastc[i] = cf;
  }
}

// ---- K123: fused conv1+conv2+conv3, LDS-swizzled intermediates, writes C ----
// sImg: [3][64][64] u16 with per-row rotation: element (ch,y,x) at
//       ch*4096 + y*64 + ((x + (y&3)*16) & 63)  -> ky-rows hit disjoint banks.
// sA:   [225][32] u16, column-group XOR: (pix,oc) at
//       pix*32 + (((oc>>3) ^ ((pix>>1)&3))<<3) + (oc&7)
// sBv:  [36][64] u16, (pix,oc) at pix*64 + (((oc>>3) ^ (pix&7))<<3) + (oc&7)
// sBv aliases sImg (dead after conv1) -> 38,976 B LDS -> 4 blocks/CU.
__global__ __launch_bounds__(256) void k_conv123(const void* img,
                                                 const u16* __restrict__ W1F, const void* b1,
                                                 const u16* __restrict__ W2F, const void* b2,
                                                 const u16* __restrict__ W3F, const void* b3,
                                                 u16* __restrict__ out, const int* flag){
  __shared__ __align__(16) u16 smem[19488];
  u16* sImg = smem;            // 12288 u16
  u16* sA   = smem + 12288;    // 7200 u16
  u16* sBv  = smem;            // 2304 u16, overlays sImg after conv1
  bool f32 = (*flag != 0);
  int n = blockIdx.x, tid = threadIdx.x;
  // stage image -> bf16 LDS (row-rotated)
  if (f32){
    const float4* ip = (const float4*)((const float*)img + (size_t)n*12288);
    for (int i = tid; i < 3072; i += 256){
      float4 v = ip[i];
      ushort4 u; u.x = fbf(v.x); u.y = fbf(v.y); u.z = fbf(v.z); u.w = fbf(v.w);
      int L = i*4;
      int addr = (L & ~63) | (((L & 63) + (((L >> 6) & 3) << 4)) & 63);
      *(ushort4*)(sImg + addr) = u;
    }
  } else {
    const ushort4* ip = (const ushort4*)((const u16*)img + (size_t)n*12288);
    for (int i = tid; i < 3072; i += 256){
      ushort4 u = ip[i];
      int L = i*4;
      int addr = (L & ~63) | (((L & 63) + (((L >> 6) & 3) << 4)) & 63);
      *(ushort4*)(sImg + addr) = u;
    }
  }
  int wv = tid >> 6, lane = tid & 63;
  int mi = lane & 15, q = lane >> 4;

  // ---- conv1: M=225 (16 tiles, 4/wave), N=32 (2 tiles), K=192 (6 steps) ----
  short8v bfr1[2][6];
  #pragma unroll
  for (int nt = 0; nt < 2; ++nt)
    #pragma unroll
    for (int s = 0; s < 6; ++s)
      bfr1[nt][s] = ((const short8v*)W1F)[(nt*6+s)*64 + lane];
  float b1v[2];
  #pragma unroll
  for (int nt = 0; nt < 2; ++nt)
    b1v[nt] = f32 ? ((const float*)b1)[nt*16+mi] : bfv(((const u16*)b1)[nt*16+mi]);
  __syncthreads();

  {
    f32x4 acc[4][2];
    #pragma unroll
    for (int mt = 0; mt < 4; ++mt)
      #pragma unroll
      for (int nt = 0; nt < 2; ++nt)
        acc[mt][nt] = (f32x4){0.f,0.f,0.f,0.f};
    int base[4];
    #pragma unroll
    for (int mt = 0; mt < 4; ++mt){
      int m = (wv*4+mt)*16 + mi;
      int mc = m < 225 ? m : 224;
      int oy = mc/15, ox = mc - oy*15;
      base[mt] = oy*256 + ox*4;
    }
    for (int s = 0; s < 6; ++s){
      int cky = 4*s + q;
      int off = (cky >> 3)*4096 + (cky & 7)*64;
      #pragma unroll
      for (int mt = 0; mt < 4; ++mt){
        int Lb = base[mt] + off;
        const u16* rp = sImg + (Lb & ~63);
        int x0 = Lb & 63;
        int rot = ((Lb >> 6) & 3) << 4;
        short4v lo = *(const short4v*)(rp + ((x0 + rot) & 63));
        short4v hi = *(const short4v*)(rp + ((x0 + 4 + rot) & 63));
        short8v a = __builtin_shufflevector(lo, hi, 0,1,2,3,4,5,6,7);
        acc[mt][0] = __builtin_amdgcn_mfma_f32_16x16x32_bf16(a, bfr1[0][s], acc[mt][0], 0,0,0);
        acc[mt][1] = __builtin_amdgcn_mfma_f32_16x16x32_bf16(a, bfr1[1][s], acc[mt][1], 0,0,0);
      }
    }
    __syncthreads();   // sImg reads done before sBv (alias) writes in conv2
    #pragma unroll
    for (int mt = 0; mt < 4; ++mt){
      int mrow0 = (wv*4+mt)*16 + q*4;
      #pragma unroll
      for (int nt = 0; nt < 2; ++nt){
        int oc = nt*16 + mi;
        #pragma unroll
        for (int r = 0; r < 4; ++r){
          int m = mrow0 + r;
          if (m < 225){
            int g = ((oc >> 3) ^ ((m >> 1) & 3)) << 3;
            sA[m*32 + g + (oc & 7)] = fbf(fmaxf(acc[mt][nt][r] + b1v[nt], 0.f));
          }
        }
      }
    }
  }
  __syncthreads();

  // ---- conv2: M=36 (3 tiles), N=64 (wave-per-tile), K=512 (16 steps) ----
  {
    short8v bfr2[16];
    #pragma unroll
    for (int s = 0; s < 16; ++s)
      bfr2[s] = ((const short8v*)W2F)[(wv*16+s)*64 + lane];
    int oc = wv*16 + mi;
    float bv = f32 ? ((const float*)b2)[oc] : bfv(((const u16*)b2)[oc]);
    f32x4 acc[3];
    #pragma unroll
    for (int mt = 0; mt < 3; ++mt) acc[mt] = (f32x4){0.f,0.f,0.f,0.f};
    int pixb[3];
    #pragma unroll
    for (int mt = 0; mt < 3; ++mt){
      int m = mt*16 + mi; if (m > 35) m = 35;
      int oy = m/6, ox = m - oy*6;
      pixb[mt] = oy*30 + ox*2;
    }
    #pragma unroll
    for (int s = 0; s < 16; ++s){
      int dp = (s>>2)*15 + (s&3);
      #pragma unroll
      for (int mt = 0; mt < 3; ++mt){
        int pix = pixb[mt] + dp;
        int g = (q ^ ((pix >> 1) & 3)) << 3;
        short8v a = *(const short8v*)(sA + pix*32 + g);
        acc[mt] = __builtin_amdgcn_mfma_f32_16x16x32_bf16(a, bfr2[s], acc[mt], 0,0,0);
      }
    }
    __syncthreads();   // sA reads done before next phase (no alias, but cheap safety)
    #pragma unroll
    for (int mt = 0; mt < 3; ++mt)
      #pragma unroll
      for (int r = 0; r < 4; ++r){
        int m = mt*16 + q*4 + r;
        if (m < 36){
          int g = ((oc >> 3) ^ (m & 7)) << 3;
          sBv[m*64 + g + (oc & 7)] = fbf(fmaxf(acc[mt][r] + bv, 0.f));
        }
      }
  }
  __syncthreads();

  // ---- conv3: M=16, N=64, K=576 (18 steps) ----
  {
    int oy = mi >> 2, ox = mi & 3;
    int oc = wv*16 + mi;
    float bv = f32 ? ((const float*)b3)[oc] : bfv(((const u16*)b3)[oc]);
    short8v bfr3[18];
    #pragma unroll
    for (int s = 0; s < 18; ++s)
      bfr3[s] = ((const short8v*)W3F)[(wv*18+s)*64 + lane];
    f32x4 acc = (f32x4){0.f,0.f,0.f,0.f};
    #pragma unroll
    for (int s = 0; s < 18; ++s){
      int pair = s >> 1, ky = pair/3, kx = pair - ky*3;
      int pix = (oy+ky)*6 + ox+kx;
      int g = ((((s & 1) << 2) | q) ^ (pix & 7)) << 3;
      short8v a = *(const short8v*)(sBv + pix*64 + g);
      acc = __builtin_amdgcn_mfma_f32_16x16x32_bf16(a, bfr3[s], acc, 0,0,0);
    }
    u16* ob = out + (size_t)n*1024;
    #pragma unroll
    for (int r = 0; r < 4; ++r)
      ob[(q*4+r)*64 + oc] = fbf(fmaxf(acc[r] + bv, 0.f));
  }
}

// ---- K4: fc MFMA GEMM 1024x512x1024 + ReLU -> H[samp][517] fp32 ----
__global__ __launch_bounds__(256) void k_fc(const u16* __restrict__ C, const u16* __restrict__ FWF,
                                            const void* fb, float* __restrict__ H, const int* flag){
  bool f32 = (*flag != 0);
  int wv = threadIdx.x >> 6, lane = threadIdx.x & 63;
  int mi = lane & 15, q = lane >> 4;
  int mt = blockIdx.x >> 3;               // 0..63
  int nt = (blockIdx.x & 7)*4 + wv;       // 0..31
  const u16* ap = C + (size_t)(mt*16 + mi)*1024 + q*8;
  const short8v* bp = (const short8v*)FWF + (size_t)nt*32*64 + lane;
  f32x4 acc0 = (f32x4){0.f,0.f,0.f,0.f};
  f32x4 acc1 = (f32x4){0.f,0.f,0.f,0.f};
  #pragma unroll
  for (int kt = 0; kt < 32; kt += 2){
    short8v a0 = *(const short8v*)(ap + kt*32);
    short8v b0 = bp[kt*64];
    short8v a1 = *(const short8v*)(ap + (kt+1)*32);
    short8v b1 = bp[(kt+1)*64];
    acc0 = __builtin_amdgcn_mfma_f32_16x16x32_bf16(a0, b0, acc0, 0,0,0);
    acc1 = __builtin_amdgcn_mfma_f32_16x16x32_bf16(a1, b1, acc1, 0,0,0);
  }
  int o = nt*16 + mi;
  float bv = f32 ? ((const float*)fb)[o] : bfv(((const u16*)fb)[o]);
  #pragma unroll
  for (int r = 0; r < 4; ++r){
    int m = mt*16 + q*4 + r;
    H[(size_t)m*MAPD + o] = fmaxf(acc0[r] + acc1[r] + bv, 0.f);
  }
}

// ---- K0: transpose w1 (128 x 132352) into WT[p][c][j] bf16 ----
template<bool F32> __device__ void wt_body(const void* pw1, const void* vw1, u16* wt, u32* tile){
  int c  = blockIdx.x >> 1;
  int ph = blockIdx.x & 1;
  for (int it = 0; it < 4; ++it){
    int idx = it*256 + threadIdx.x;        // [0,1024)
    int jp = idx >> 4, pg = idx & 15;      // jp: 64 j-pairs, pg: 16 pp-groups of 8
    int j0 = jp*2;
    const void* w = (j0 < 64) ? pw1 : vw1;
    int jj0 = (j0 < 64) ? j0 : j0-64;
    size_t base0 = (size_t)jj0*FLATD + c*P_ + ph*128 + pg*8;
    size_t base1 = base0 + FLATD;
    u16 a[8], b[8];
    if constexpr (F32){
      const float* f = (const float*)w;
      float4 a0 = *(const float4*)(f + base0), a1 = *(const float4*)(f + base0 + 4);
      float4 b0 = *(const float4*)(f + base1), b1 = *(const float4*)(f + base1 + 4);
      a[0]=fbf(a0.x); a[1]=fbf(a0.y); a[2]=fbf(a0.z); a[3]=fbf(a0.w);
      a[4]=fbf(a1.x); a[5]=fbf(a1.y); a[6]=fbf(a1.z); a[7]=fbf(a1.w);
      b[0]=fbf(b0.x); b[1]=fbf(b0.y); b[2]=fbf(b0.z); b[3]=fbf(b0.w);
      b[4]=fbf(b1.x); b[5]=fbf(b1.y); b[6]=fbf(b1.z); b[7]=fbf(b1.w);
    } else {
      short8v va = *(const short8v*)((const u16*)w + base0);
      short8v vb = *(const short8v*)((const u16*)w + base1);
      #pragma unroll
      for (int k = 0; k < 8; ++k){ a[k] = (u16)va[k]; b[k] = (u16)vb[k]; }
    }
    int slot = (jp >> 2) ^ pg;             // pp>>3 == pg for all 8 rows of this lane
    int sub  = jp & 3;
    #pragma unroll
    for (int k = 0; k < 8; ++k){
      int pp = pg*8 + k;
      tile[pp*64 + slot*4 + sub] = (u32)a[k] | ((u32)b[k] << 16);
    }
  }
  __syncthreads();
  for (int it = 0; it < 8; ++it){
    int idx = it*256 + threadIdx.x;        // [0,2048)
    int pp = idx >> 4, jb = idx & 15;
    int slot = jb ^ ((pp >> 3) & 15);
    u32x4 v = *(const u32x4*)(tile + pp*64 + slot*4);
    int p = ph*128 + pp;
    *(u32x4*)(wt + ((size_t)p*MAPD + c)*128 + jb*8) = v;
  }
}
__global__ __launch_bounds__(256) void k_wt(const void* pw1, const void* vw1, u16* wt, const int* flag){
  __shared__ u32 tile[128*64];             // 32 KB, swizzled
  if (*flag) wt_body<true>(pw1,vw1,wt,tile); else wt_body<false>(pw1,vw1,wt,tile);
}

// ---- K6: y_init partials: PARTB[block][b][j] (bf16), no atomics ----
template<int CLEN>
__device__ __forceinline__ void yloop(const u16* __restrict__ wp, const float* __restrict__ sSb,
                                      float (&acc)[8][2]){
  #pragma unroll 10
  for (int c = 0; c < CLEN; ++c){
    u32 w = *(const u32*)(wp + (size_t)c*128);            // global, 256 B/wave, L1-shared
    float w0 = bfv((u16)(w & 0xffffu)), w1 = bfv((u16)(w >> 16));
    const float4* s4 = (const float4*)(sSb + c*32);       // LDS broadcast (free)
    float4 sa = s4[0], sb = s4[1];
    float sv[8] = {sa.x,sa.y,sa.z,sa.w,sb.x,sb.y,sb.z,sb.w};
    #pragma unroll
    for (int bb = 0; bb < 8; ++bb){
      acc[bb][0] += sv[bb]*w0;
      acc[bb][1] += sv[bb]*w1;
    }
  }
}
__global__ __launch_bounds__(256) void k_yinit(const u16* __restrict__ ST0T, const u16* __restrict__ wt,
                                               u16* __restrict__ PARTB){
  __shared__ float sS[130*32];   // 16.6 KB -> high occupancy
  int p = blockIdx.x >> 2, cq = blockIdx.x & 3;
  int c0 = cq*130;
  int clen = (cq == 3) ? 127 : 130;
  const ushort4* ssrc = (const ushort4*)(ST0T + ((size_t)p*MAPD + c0)*32);
  int n4 = clen*8;
  for (int i = threadIdx.x; i < n4; i += 256){
    ushort4 u = ssrc[i];
    float4 f; f.x = bfv(u.x); f.y = bfv(u.y); f.z = bfv(u.z); f.w = bfv(u.w);
    *(float4*)(sS + i*4) = f;
  }
  __syncthreads();
  int jg = threadIdx.x & 63, bg = threadIdx.x >> 6;
  int j0 = jg*2, b0 = bg*8;
  const u16* wp = wt + ((size_t)p*MAPD + c0)*128 + j0;
  float acc[8][2] = {};
  if (cq < 3) yloop<130>(wp, sS + b0, acc);
  else        yloop<127>(wp, sS + b0, acc);
  u32* op = (u32*)(PARTB + (size_t)blockIdx.x*4096);
  #pragma unroll
  for (int bb = 0; bb < 8; ++bb){
    u32 pk = (u32)fbf(acc[bb][0]) | ((u32)fbf(acc[bb][1]) << 16);
    op[((b0+bb)*128 + j0) >> 1] = pk;
  }
}

// ---- K6b: reduce 1024 partials -> YI (fp32) ----
__global__ __launch_bounds__(256) void k_yred(const u16* __restrict__ PARTB, float* __restrict__ YI){
  int o = blockIdx.x*64 + (threadIdx.x & 63);
  int kq = threadIdx.x >> 6;
  float s = 0.f;
  const u16* pp = PARTB + (size_t)kq*256*4096 + o;
  #pragma unroll 8
  for (int k = 0; k < 256; ++k) s += bfv(pp[(size_t)k*4096]);
  __shared__ float red[256];
  red[threadIdx.x] = s;
  __syncthreads();
  if (threadIdx.x < 64)
    YI[o] = red[threadIdx.x] + red[threadIdx.x+64] + red[threadIdx.x+128] + red[threadIdx.x+192];
}

// ---- K7: delta partial dots; grid (n x 4 c-chunks), j-paired u32 loads,
//      block's two waves split the c-chunk -> DLT8[(n*4+cq)*2+half][j] ----
__global__ __launch_bounds__(128) void k_delta(const float* __restrict__ H, const u16* __restrict__ wt,
                                               const u16* __restrict__ st0t,
                                               const int* __restrict__ pos, const void* done,
                                               const int* __restrict__ prev, const float* __restrict__ coef,
                                               float* __restrict__ dlt8, const int* flag){
  __shared__ float diff[132];
  bool f32 = (*flag != 0);
  int n = blockIdx.x >> 2, cq = blockIdx.x & 3;
  int c0 = cq*130, clen = (cq == 3) ? 127 : 130;
  int b = n & 31;
  int p = pos[n*2]*16 + pos[n*2+1];
  float dn = f32 ? ((const float*)done)[n] : bfv(((const u16*)done)[n]);
  float m = 1.f - dn;
  int pv = prev[n];
  float cf = coef[n]*m;
  const float* hc = H + (size_t)n*MAPD + c0;
  for (int c = threadIdx.x; c < clen; c += 128){
    float old;
    if (pv >= 0) old = H[(size_t)(pv*32 + b)*MAPD + c0 + c];
    else         old = bfv(st0t[((size_t)p*MAPD + c0 + c)*32 + b]);
    diff[c] = hc[c] - cf*old;
  }
  __syncthreads();
  int half = threadIdx.x >> 6, jp = threadIdx.x & 63, j0 = jp*2;
  int hbase, hlen;
  if (cq == 3){ hbase = half*64; hlen = half ? 63 : 64; }
  else        { hbase = half*65; hlen = 65; }
  const u16* wp = wt + ((size_t)p*MAPD + c0 + hbase)*128 + j0;
  const float* dptr = diff + hbase;
  float a0 = 0.f, a1 = 0.f;
  int c = 0;
  for (; c + 4 <= hlen; c += 4){
    u32 w0 = *(const u32*)(wp + (size_t)(c+0)*128);
    u32 w1 = *(const u32*)(wp + (size_t)(c+1)*128);
    u32 w2 = *(const u32*)(wp + (size_t)(c+2)*128);
    u32 w3 = *(const u32*)(wp + (size_t)(c+3)*128);
    float d0 = dptr[c], d1 = dptr[c+1], d2 = dptr[c+2], d3 = dptr[c+3];
    a0 += d0*bfv((u16)(w0 & 0xffffu)) + d1*bfv((u16)(w1 & 0xffffu))
        + d2*bfv((u16)(w2 & 0xffffu)) + d3*bfv((u16)(w3 & 0xffffu));
    a1 += d0*bfv((u16)(w0 >> 16)) + d1*bfv((u16)(w1 >> 16))
        + d2*bfv((u16)(w2 >> 16)) + d3*bfv((u16)(w3 >> 16));
  }
  for (; c < hlen; ++c){
    u32 w = *(const u32*)(wp + (size_t)c*128);
    a0 += dptr[c]*bfv((u16)(w & 0xffffu));
    a1 += dptr[c]*bfv((u16)(w >> 16));
  }
  f32x2 st; st[0] = a0; st[1] = a1;
  *(f32x2*)(dlt8 + ((size_t)blockIdx.x*2 + half)*128 + j0) = st;
}

// ---- K8a: barrier-free 32-step scan -> TH[n][128] fp32 ----
__global__ __launch_bounds__(128) void k_scan(const float* __restrict__ yi,
                                              const float* __restrict__ dlt8, const void* done,
                                              const void* pb1, const void* vb1,
                                              float* __restrict__ TH, const int* flag){
  bool f32 = (*flag != 0);
  int b = blockIdx.x, j = threadIdx.x;
  float y = yi[b*128 + j];
  float bias = (j < 64) ? (f32 ? ((const float*)pb1)[j]    : bfv(((const u16*)pb1)[j]))
                        : (f32 ? ((const float*)vb1)[j-64] : bfv(((const u16*)vb1)[j-64]));
  for (int t = 0; t < T_; ++t){
    int n = t*32 + b;
    float m = 1.f - (f32 ? ((const float*)done)[n] : bfv(((const u16*)done)[n]));
    const float* dp = dlt8 + (size_t)n*1024 + j;
    float d = dp[0] + dp[128] + dp[256] + dp[384]
            + dp[512] + dp[640] + dp[768] + dp[896];
    y = m*y + d;
    TH[(size_t)n*128 + j] = tanhf(y + bias);
  }
}

// ---- K8b: head matvecs from TH (wave per sample, shuffle reduce) ----
__global__ __launch_bounds__(256) void k_heads(const float* __restrict__ TH,
                                               const void* pw2, const void* pb2,
                                               const void* vw2, const void* vb2,
                                               void* out, const int* flag){
  bool f32 = (*flag != 0);
  int wv = threadIdx.x >> 6, lane = threadIdx.x & 63;
  int n = blockIdx.x*4 + wv;
  const float* th = TH + (size_t)n*128;
  float tq = th[lane];
  float tv = th[64 + lane];
  float acc[6];
  #pragma unroll
  for (int j = 0; j < 5; ++j)
    acc[j] = tq * (f32 ? ((const float*)pw2)[j*64 + lane] : bfv(((const u16*)pw2)[j*64 + lane]));
  acc[5] = tv * (f32 ? ((const float*)vw2)[lane] : bfv(((const u16*)vw2)[lane]));
  #pragma unroll
  for (int off = 32; off > 0; off >>= 1)
    #pragma unroll
    for (int j = 0; j < 6; ++j)
      acc[j] += __shfl_down(acc[j], off, 64);
  if (lane == 0){
    #pragma unroll
    for (int j = 0; j < 5; ++j){
      float s = acc[j] + (f32 ? ((const float*)pb2)[j] : bfv(((const u16*)pb2)[j]));
      if (f32) ((float*)out)[n*5 + j] = s; else ((u16*)out)[n*5 + j] = fbf(s);
    }
    float s = acc[5] + (f32 ? ((const float*)vb2)[0] : bfv(((const u16*)vb2)[0]));
    if (f32) ((float*)out)[5120 + n] = s; else ((u16*)out)[5120 + n] = fbf(s);
  }
}

// ---- K9: final_state closed form ----
template<bool F32> __device__ void final_body(const float* H, const void* st0,
                                              const int* lastw, const float* lastc, void* out){
  size_t i = (size_t)blockIdx.x*256 + threadIdx.x;
  if (i >= (size_t)B_*FLATD) return;
  int b = (int)(i / FLATD);
  int r = (int)(i - (size_t)b*FLATD);
  int c = r >> 8, p = r & 255;
  int lw = lastw[b*256 + p];
  float lc = lastc[b*256 + p];
  float v;
  if (lw >= 0) v = H[(size_t)(lw*32 + b)*MAPD + c]*lc;
  else         v = ld<F32>(st0, i)*lc;
  if constexpr (F32) ((float*)out)[6144 + i] = v; else ((u16*)out)[6144 + i] = fbf(v);
}
__global__ __launch_bounds__(256) void k_final(const float* H, const void* st0,
                                               const int* lastw, const float* lastc, void* out,
                                               const int* flag){
  if (*flag) final_body<true>(H,st0,lastw,lastc,out); else final_body<false>(H,st0,lastw,lastc,out);
}

extern "C" void kernel_launch(void* const* d_in, const int* in_sizes, int n_in,
                              void* d_out, int out_size, void* d_ws, size_t ws_size,
                              hipStream_t stream) {
  (void)in_sizes; (void)n_in; (void)out_size; (void)ws_size;
  const void* image = d_in[0];
  const int*  lact  = (const int*)d_in[1];
  const int*  pos   = (const int*)d_in[2];
  const void* done  = d_in[3];
  const void* st0   = d_in[4];
  const void* c1w = d_in[5];  const void* c1b = d_in[6];
  const void* c2w = d_in[7];  const void* c2b = d_in[8];
  const void* c3w = d_in[9];  const void* c3b = d_in[10];
  const void* fcw = d_in[11]; const void* fcb = d_in[12];
  const void* pw1 = d_in[13]; const void* pb1 = d_in[14];
  const void* pw2 = d_in[15]; const void* pb2 = d_in[16];
  const void* vw1 = d_in[17]; const void* vb1 = d_in[18];
  const void* vw2 = d_in[19]; const void* vb2 = d_in[20];
  char* ws = (char*)d_ws;

  // workspace (~54.7 MB). WT overlays C; DLT8 overlays PARTB (dead after k_yred).
  u16*   WT    = (u16*)  (ws + 0);           // 33,882,112
  u16*   C     = (u16*)  (ws + 19464192);    // 2,097,152 (overlays WT tail region used later)
  float* H     = (float*)(ws + 33882368);    // 2,117,632
  float* YI    = (float*)(ws + 36000256);    // 16,384
  u16*   PARTB = (u16*)  (ws + 36016640);    // 8,388,608 (1024*4096 bf16)
  float* DLT8  = (float*)(ws + 36016640);    // 4,194,304 (overlays PARTB, used after yred)
  int*   PREV  = (int*)  (ws + 44405248);
  float* COEF  = (float*)(ws + 44409344);
  int*   LASTW = (int*)  (ws + 44413440);
  float* LASTC = (float*)(ws + 44446208);
  int*   FLAG  = (int*)  (ws + 44478976);
  u16*   W1F   = (u16*)  (ws + 44479232);    // 12,288
  u16*   W2F   = (u16*)  (ws + 44491520);    // 65,536
  u16*   W3F   = (u16*)  (ws + 44557056);    // 73,728
  u16*   FWF   = (u16*)  (ws + 44630784);    // 1,048,576 (MFMA B-frags of fcw)
  u16*   ST0T  = (u16*)  (ws + 45679360);    // 8,470,528
  float* TH    = (float*)(ws + 54149888);    // 524,288 -> 54,674,176

  k_probe<<<1, 64, 0, stream>>>(image, FLAG);
  k_prep <<<684, 256, 0, stream>>>(c1w, c2w, c3w, fcw, st0, W1F, W2F, W3F, FWF, ST0T, FLAG);
  k_meta <<<36, 256, 0, stream>>>(pos, done, lact, PREV, COEF, H, LASTW, LASTC, FLAG);
  k_conv123<<<1024, 256, 0, stream>>>(image, W1F, c1b, W2F, c2b, W3F, c3b, C, FLAG);
  k_fc   <<<512, 256, 0, stream>>>(C, FWF, fcb, H, FLAG);
  k_wt   <<<1034, 256, 0, stream>>>(pw1, vw1, WT, FLAG);
  k_yinit<<<1024, 256, 0, stream>>>(ST0T, WT, PARTB);
  k_yred <<<64, 256, 0, stream>>>(PARTB, YI);
  k_delta<<<4096, 128, 0, stream>>>(H, WT, ST0T, pos, done, PREV, COEF, DLT8, FLAG);
  k_scan <<<32, 128, 0, stream>>>(YI, DLT8, done, pb1, vb1, TH, FLAG);
  k_heads<<<256, 256, 0, stream>>>(TH, pw2, pb2, vw2, vb2, d_out, FLAG);
  k_final<<<16544, 256, 0, stream>>>(H, st0, LASTW, LASTC, d_out, FLAG);
}

// Round 5
// 358.910 us; speedup vs baseline: 1.0253x; 1.0253x over previous
//
#include <hip/hip_runtime.h>

#define T_ 32
#define B_ 32
#define MAPD 517
#define P_ 256
#define FLATD (MAPD*P_)   // 132352
#define TBN (T_*B_)       // 1024

typedef unsigned short u16;
typedef unsigned int u32;
typedef __attribute__((ext_vector_type(4))) short short4v;
typedef __attribute__((ext_vector_type(8))) short short8v;
typedef __attribute__((ext_vector_type(4))) float f32x4;
typedef __attribute__((ext_vector_type(2))) float f32x2;
typedef __attribute__((ext_vector_type(4))) u32 u32x4;

__device__ __forceinline__ float bfv(u16 u){ u32 x = ((u32)u)<<16; return __uint_as_float(x); }
__device__ __forceinline__ u16 fbf(float f){
  u32 x = __float_as_uint(f);
  return (u16)((x + 0x7fffu + ((x>>16)&1u))>>16);
}
template<bool F32> __device__ __forceinline__ float ld(const void* p, size_t i){
  if constexpr (F32) return ((const float*)p)[i];
  else               return bfv(((const u16*)p)[i]);
}

// ---- dtype probe: 1 if float inputs are fp32, 0 if bf16 ----
__global__ void k_probe(const void* img, int* flag){
  if (threadIdx.x == 0 && blockIdx.x == 0){
    const u16* u = (const u16*)img;
    int cnt = 0;
    for (int i = 0; i < 256; ++i) if (u[i] <= 0x4380u) ++cnt;
    *flag = (cnt < 240) ? 1 : 0;
  }
}

// ---- K-prep (fused): conv frag layouts + FWF (fc MFMA B-frags) + ST0T transpose ----
__global__ __launch_bounds__(256) void k_prep(const void* c1w, const void* c2w, const void* c3w,
                                              const void* fcw, const void* st0,
                                              u16* W1F, u16* W2F, u16* W3F, u16* FWF, u16* ST0T,
                                              const int* flag){
  __shared__ __align__(16) char smem_[32768];
  bool f32 = (*flag != 0);
  int bid = blockIdx.x, tid = threadIdx.x;
  if (bid < 24){
    int idx = bid*256 + tid;                   // 6144
    int j = idx & 7, l = (idx>>3) & 63, t = idx>>9;
    int nt = t/6, s = t - nt*6;
    int oc = nt*16 + (l&15);
    int kk = 8*(4*s + (l>>4)) + j;
    float v = f32 ? ((const float*)c1w)[oc*192+kk] : bfv(((const u16*)c1w)[oc*192+kk]);
    W1F[idx] = fbf(v);
  } else if (bid < 152){
    int idx = (bid-24)*256 + tid;              // 32768
    int j = idx & 7, l = (idx>>3) & 63, s = (idx>>9) & 15, nt = idx>>13;
    int oc = nt*16 + (l&15);
    int cin = (l>>4)*8 + j;
    int src = oc*512 + cin*16 + (s>>2)*4 + (s&3);
    float v = f32 ? ((const float*)c2w)[src] : bfv(((const u16*)c2w)[src]);
    W2F[idx] = fbf(v);
  } else if (bid < 296){
    int idx = (bid-152)*256 + tid;             // 36864
    int j = idx & 7, l = (idx>>3) & 63, t = idx>>9;   // t = nt*18+s
    int nt = t/18, s = t - nt*18;
    int oc = nt*16 + (l&15);
    int c = (s&1)*32 + (l>>4)*8 + j;
    int src = oc*576 + c*9 + (s>>1);
    float v = f32 ? ((const float*)c3w)[src] : bfv(((const u16*)c3w)[src]);
    W3F[idx] = fbf(v);
  } else if (bid < 424){
    // FWF: MFMA B-fragments of fc_w for k_fc.
    int b = bid - 296;                          // 128 blocks x 4096 elems
    for (int it = 0; it < 16; ++it){
      int idx = (b*16 + it)*256 + tid;          // 524288 total
      int j = idx & 7, l = (idx>>3) & 63, frag = idx >> 9;
      int nt = frag >> 5, kt = frag & 31;
      int kc = kt*32 + ((l>>4)<<3) + j;
      int kr = (kc & 63)*16 + (kc >> 6);
      int o  = nt*16 + (l & 15);
      float v = f32 ? ((const float*)fcw)[(size_t)o*1024 + kr]
                    : bfv(((const u16*)fcw)[(size_t)o*1024 + kr]);
      FWF[idx] = fbf(v);
    }
  } else {
    // ST0T[p][c][b] transpose
    u16* tile = (u16*)smem_;                   // 32,768 B
    int b0 = bid - 424;                        // 260 blocks
    int c0 = (b0 >> 2)*8, p0 = (b0 & 3)*64;
    for (int it = 0; it < 64; ++it){
      int idx = it*256 + tid;
      int pl = idx & 63, b = (idx>>6)&31, ci = idx>>11;
      int c = c0 + ci;
      float v = 0.f;
      if (c < MAPD)
        v = f32 ? ((const float*)st0)[((size_t)b*MAPD+c)*256 + p0+pl]
                : bfv(((const u16*)st0)[((size_t)b*MAPD+c)*256 + p0+pl]);
      tile[ci*2048 + pl*32 + b] = fbf(v);
    }
    __syncthreads();
    for (int it = 0; it < 64; ++it){
      int idx = it*256 + tid;
      int b = idx & 31, ci = (idx>>5)&7, pl = idx>>8;
      int c = c0 + ci;
      if (c < MAPD)
        ST0T[((size_t)(p0+pl)*MAPD + c)*32 + b] = tile[ci*2048 + pl*32 + b];
    }
  }
}

// ---- K-meta (fused): prev-writer/coef + one-hot into H ; last-writer/coef ----
__global__ void k_meta(const int* pos, const void* done, const int* lact,
                       int* prev, float* coef, float* H, int* lastw, float* lastc, const int* flag){
  bool f32 = (*flag != 0);
  int bid = blockIdx.x;
  if (bid < 4){
    int i = bid*256 + threadIdx.x;
    int t = i >> 5, b = i & 31;
    int p = pos[i*2]*16 + pos[i*2+1];
    int pv = -1;
    for (int s = t-1; s >= 0; --s){
      int n = s*32 + b;
      if (pos[n*2]*16 + pos[n*2+1] == p){ pv = s; break; }
    }
    float cf = 1.f;
    for (int s = (pv<0?0:pv+1); s <= t-1; ++s)
      cf *= (1.f - (f32 ? ((const float*)done)[s*32+b] : bfv(((const u16*)done)[s*32+b])));
    prev[i] = pv; coef[i] = cf;
    int la = lact[i];
    #pragma unroll
    for (int a = 0; a < 5; ++a) H[(size_t)i*MAPD + 512 + a] = (la == a) ? 1.f : 0.f;
  } else {
    int i = (bid-4)*256 + threadIdx.x;
    int b = i >> 8, p = i & 255;
    int lw = -1;
    for (int s = T_-1; s >= 0; --s){
      int n = s*32 + b;
      if (pos[n*2]*16 + pos[n*2+1] == p){ lw = s; break; }
    }
    float cf = 1.f;
    for (int s = (lw<0?0:lw+1); s < T_; ++s)
      cf *= (1.f - (f32 ? ((const float*)done)[s*32+b] : bfv(((const u16*)done)[s*32+b])));
    lastw[i] = lw; lastc[i] = cf;
  }
}

// ---- K123: fused conv1+conv2+conv3, weight-prefetch pipelined across phases ----
// __launch_bounds__(256,4): 128-VGPR budget (LDS caps at 4 blocks/CU anyway) so the
// compiler can keep full weight-fragment sets resident instead of streaming them
// just-in-time (76-VGPR version serialized ~46 L2 latencies per wave).
// bfr2 loads issued after conv1's MFMA loop (bfr1 dead); bfr3 after conv2's.
__global__ __launch_bounds__(256, 4) void k_conv123(const void* img,
                                                 const u16* __restrict__ W1F, const void* b1,
                                                 const u16* __restrict__ W2F, const void* b2,
                                                 const u16* __restrict__ W3F, const void* b3,
                                                 u16* __restrict__ out, const int* flag){
  __shared__ __align__(16) u16 smem[19488];
  u16* sImg = smem;            // 12288 u16
  u16* sA   = smem + 12288;    // 7200 u16
  u16* sBv  = smem;            // 2304 u16, overlays sImg after conv1
  bool f32 = (*flag != 0);
  int n = blockIdx.x, tid = threadIdx.x;
  // stage image -> bf16 LDS (row-rotated)
  if (f32){
    const float4* ip = (const float4*)((const float*)img + (size_t)n*12288);
    for (int i = tid; i < 3072; i += 256){
      float4 v = ip[i];
      ushort4 u; u.x = fbf(v.x); u.y = fbf(v.y); u.z = fbf(v.z); u.w = fbf(v.w);
      int L = i*4;
      int addr = (L & ~63) | (((L & 63) + (((L >> 6) & 3) << 4)) & 63);
      *(ushort4*)(sImg + addr) = u;
    }
  } else {
    const ushort4* ip = (const ushort4*)((const u16*)img + (size_t)n*12288);
    for (int i = tid; i < 3072; i += 256){
      ushort4 u = ip[i];
      int L = i*4;
      int addr = (L & ~63) | (((L & 63) + (((L >> 6) & 3) << 4)) & 63);
      *(ushort4*)(sImg + addr) = u;
    }
  }
  int wv = tid >> 6, lane = tid & 63;
  int mi = lane & 15, q = lane >> 4;

  short8v bfr2[16];
  short8v bfr3[18];

  // ---- conv1: M=225 (16 tiles, 4/wave), N=32 (2 tiles), K=192 (6 steps) ----
  short8v bfr1[2][6];
  #pragma unroll
  for (int nt = 0; nt < 2; ++nt)
    #pragma unroll
    for (int s = 0; s < 6; ++s)
      bfr1[nt][s] = ((const short8v*)W1F)[(nt*6+s)*64 + lane];
  float b1v[2];
  #pragma unroll
  for (int nt = 0; nt < 2; ++nt)
    b1v[nt] = f32 ? ((const float*)b1)[nt*16+mi] : bfv(((const u16*)b1)[nt*16+mi]);
  __syncthreads();

  {
    f32x4 acc[4][2];
    #pragma unroll
    for (int mt = 0; mt < 4; ++mt)
      #pragma unroll
      for (int nt = 0; nt < 2; ++nt)
        acc[mt][nt] = (f32x4){0.f,0.f,0.f,0.f};
    int base[4];
    #pragma unroll
    for (int mt = 0; mt < 4; ++mt){
      int m = (wv*4+mt)*16 + mi;
      int mc = m < 225 ? m : 224;
      int oy = mc/15, ox = mc - oy*15;
      base[mt] = oy*256 + ox*4;
    }
    for (int s = 0; s < 6; ++s){
      int cky = 4*s + q;
      int off = (cky >> 3)*4096 + (cky & 7)*64;
      #pragma unroll
      for (int mt = 0; mt < 4; ++mt){
        int Lb = base[mt] + off;
        const u16* rp = sImg + (Lb & ~63);
        int x0 = Lb & 63;
        int rot = ((Lb >> 6) & 3) << 4;
        short4v lo = *(const short4v*)(rp + ((x0 + rot) & 63));
        short4v hi = *(const short4v*)(rp + ((x0 + 4 + rot) & 63));
        short8v a = __builtin_shufflevector(lo, hi, 0,1,2,3,4,5,6,7);
        acc[mt][0] = __builtin_amdgcn_mfma_f32_16x16x32_bf16(a, bfr1[0][s], acc[mt][0], 0,0,0);
        acc[mt][1] = __builtin_amdgcn_mfma_f32_16x16x32_bf16(a, bfr1[1][s], acc[mt][1], 0,0,0);
      }
    }
    // prefetch conv2 weights NOW (bfr1 dead): latency hides under sA-write + barrier
    #pragma unroll
    for (int s = 0; s < 16; ++s)
      bfr2[s] = ((const short8v*)W2F)[(wv*16+s)*64 + lane];
    __syncthreads();   // sImg reads done before sBv (alias) writes in conv2
    #pragma unroll
    for (int mt = 0; mt < 4; ++mt){
      int mrow0 = (wv*4+mt)*16 + q*4;
      #pragma unroll
      for (int nt = 0; nt < 2; ++nt){
        int oc = nt*16 + mi;
        #pragma unroll
        for (int r = 0; r < 4; ++r){
          int m = mrow0 + r;
          if (m < 225){
            int g = ((oc >> 3) ^ ((m >> 1) & 3)) << 3;
            sA[m*32 + g + (oc & 7)] = fbf(fmaxf(acc[mt][nt][r] + b1v[nt], 0.f));
          }
        }
      }
    }
  }
  __syncthreads();

  // ---- conv2: M=36 (3 tiles), N=64 (wave-per-tile), K=512 (16 steps) ----
  {
    int oc = wv*16 + mi;
    float bv = f32 ? ((const float*)b2)[oc] : bfv(((const u16*)b2)[oc]);
    f32x4 acc[3];
    #pragma unroll
    for (int mt = 0; mt < 3; ++mt) acc[mt] = (f32x4){0.f,0.f,0.f,0.f};
    int pixb[3];
    #pragma unroll
    for (int mt = 0; mt < 3; ++mt){
      int m = mt*16 + mi; if (m > 35) m = 35;
      int oy = m/6, ox = m - oy*6;
      pixb[mt] = oy*30 + ox*2;
    }
    #pragma unroll
    for (int s = 0; s < 16; ++s){
      int dp = (s>>2)*15 + (s&3);
      #pragma unroll
      for (int mt = 0; mt < 3; ++mt){
        int pix = pixb[mt] + dp;
        int g = (q ^ ((pix >> 1) & 3)) << 3;
        short8v a = *(const short8v*)(sA + pix*32 + g);
        acc[mt] = __builtin_amdgcn_mfma_f32_16x16x32_bf16(a, bfr2[s], acc[mt], 0,0,0);
      }
    }
    // prefetch conv3 weights NOW (bfr2 dead): hides under sBv-write + barrier
    #pragma unroll
    for (int s = 0; s < 18; ++s)
      bfr3[s] = ((const short8v*)W3F)[(wv*18+s)*64 + lane];
    __syncthreads();   // sA reads done before sBv writes (alias safety ordering)
    #pragma unroll
    for (int mt = 0; mt < 3; ++mt)
      #pragma unroll
      for (int r = 0; r < 4; ++r){
        int m = mt*16 + q*4 + r;
        if (m < 36){
          int g = ((oc >> 3) ^ (m & 7)) << 3;
          sBv[m*64 + g + (oc & 7)] = fbf(fmaxf(acc[mt][r] + bv, 0.f));
        }
      }
  }
  __syncthreads();

  // ---- conv3: M=16, N=64, K=576 (18 steps, dual accumulator) ----
  {
    int oy = mi >> 2, ox = mi & 3;
    int oc = wv*16 + mi;
    float bv = f32 ? ((const float*)b3)[oc] : bfv(((const u16*)b3)[oc]);
    f32x4 accA = (f32x4){0.f,0.f,0.f,0.f};
    f32x4 accB = (f32x4){0.f,0.f,0.f,0.f};
    #pragma unroll
    for (int s = 0; s < 18; s += 2){
      int pair0 = s >> 1, ky = pair0/3, kx = pair0 - ky*3;
      int pix = (oy+ky)*6 + ox+kx;
      int g0 = ((q) ^ (pix & 7)) << 3;
      int g1 = ((4 | q) ^ (pix & 7)) << 3;
      short8v a0 = *(const short8v*)(sBv + pix*64 + g0);
      short8v a1 = *(const short8v*)(sBv + pix*64 + g1);
      accA = __builtin_amdgcn_mfma_f32_16x16x32_bf16(a0, bfr3[s],   accA, 0,0,0);
      accB = __builtin_amdgcn_mfma_f32_16x16x32_bf16(a1, bfr3[s+1], accB, 0,0,0);
    }
    u16* ob = out + (size_t)n*1024;
    #pragma unroll
    for (int r = 0; r < 4; ++r)
      ob[(q*4+r)*64 + oc] = fbf(fmaxf(accA[r] + accB[r] + bv, 0.f));
  }
}

// ---- K4: fc MFMA GEMM 1024x512x1024 + ReLU -> H[samp][517] fp32 ----
__global__ __launch_bounds__(256) void k_fc(const u16* __restrict__ C, const u16* __restrict__ FWF,
                                            const void* fb, float* __restrict__ H, const int* flag){
  bool f32 = (*flag != 0);
  int wv = threadIdx.x >> 6, lane = threadIdx.x & 63;
  int mi = lane & 15, q = lane >> 4;
  int mt = blockIdx.x >> 3;               // 0..63
  int nt = (blockIdx.x & 7)*4 + wv;       // 0..31
  const u16* ap = C + (size_t)(mt*16 + mi)*1024 + q*8;
  const short8v* bp = (const short8v*)FWF + (size_t)nt*32*64 + lane;
  f32x4 acc0 = (f32x4){0.f,0.f,0.f,0.f};
  f32x4 acc1 = (f32x4){0.f,0.f,0.f,0.f};
  #pragma unroll
  for (int kt = 0; kt < 32; kt += 2){
    short8v a0 = *(const short8v*)(ap + kt*32);
    short8v b0 = bp[kt*64];
    short8v a1 = *(const short8v*)(ap + (kt+1)*32);
    short8v b1 = bp[(kt+1)*64];
    acc0 = __builtin_amdgcn_mfma_f32_16x16x32_bf16(a0, b0, acc0, 0,0,0);
    acc1 = __builtin_amdgcn_mfma_f32_16x16x32_bf16(a1, b1, acc1, 0,0,0);
  }
  int o = nt*16 + mi;
  float bv = f32 ? ((const float*)fb)[o] : bfv(((const u16*)fb)[o]);
  #pragma unroll
  for (int r = 0; r < 4; ++r){
    int m = mt*16 + q*4 + r;
    H[(size_t)m*MAPD + o] = fmaxf(acc0[r] + acc1[r] + bv, 0.f);
  }
}

// ---- K0: transpose w1 (128 x 132352) into WT[p][c][j] bf16 ----
template<bool F32> __device__ void wt_body(const void* pw1, const void* vw1, u16* wt, u32* tile){
  int c  = blockIdx.x >> 1;
  int ph = blockIdx.x & 1;
  for (int it = 0; it < 4; ++it){
    int idx = it*256 + threadIdx.x;        // [0,1024)
    int jp = idx >> 4, pg = idx & 15;      // jp: 64 j-pairs, pg: 16 pp-groups of 8
    int j0 = jp*2;
    const void* w = (j0 < 64) ? pw1 : vw1;
    int jj0 = (j0 < 64) ? j0 : j0-64;
    size_t base0 = (size_t)jj0*FLATD + c*P_ + ph*128 + pg*8;
    size_t base1 = base0 + FLATD;
    u16 a[8], b[8];
    if constexpr (F32){
      const float* f = (const float*)w;
      float4 a0 = *(const float4*)(f + base0), a1 = *(const float4*)(f + base0 + 4);
      float4 b0 = *(const float4*)(f + base1), b1 = *(const float4*)(f + base1 + 4);
      a[0]=fbf(a0.x); a[1]=fbf(a0.y); a[2]=fbf(a0.z); a[3]=fbf(a0.w);
      a[4]=fbf(a1.x); a[5]=fbf(a1.y); a[6]=fbf(a1.z); a[7]=fbf(a1.w);
      b[0]=fbf(b0.x); b[1]=fbf(b0.y); b[2]=fbf(b0.z); b[3]=fbf(b0.w);
      b[4]=fbf(b1.x); b[5]=fbf(b1.y); b[6]=fbf(b1.z); b[7]=fbf(b1.w);
    } else {
      short8v va = *(const short8v*)((const u16*)w + base0);
      short8v vb = *(const short8v*)((const u16*)w + base1);
      #pragma unroll
      for (int k = 0; k < 8; ++k){ a[k] = (u16)va[k]; b[k] = (u16)vb[k]; }
    }
    int slot = (jp >> 2) ^ pg;             // pp>>3 == pg for all 8 rows of this lane
    int sub  = jp & 3;
    #pragma unroll
    for (int k = 0; k < 8; ++k){
      int pp = pg*8 + k;
      tile[pp*64 + slot*4 + sub] = (u32)a[k] | ((u32)b[k] << 16);
    }
  }
  __syncthreads();
  for (int it = 0; it < 8; ++it){
    int idx = it*256 + threadIdx.x;        // [0,2048)
    int pp = idx >> 4, jb = idx & 15;
    int slot = jb ^ ((pp >> 3) & 15);
    u32x4 v = *(const u32x4*)(tile + pp*64 + slot*4);
    int p = ph*128 + pp;
    *(u32x4*)(wt + ((size_t)p*MAPD + c)*128 + jb*8) = v;
  }
}
__global__ __launch_bounds__(256) void k_wt(const void* pw1, const void* vw1, u16* wt, const int* flag){
  __shared__ u32 tile[128*64];             // 32 KB, swizzled
  if (*flag) wt_body<true>(pw1,vw1,wt,tile); else wt_body<false>(pw1,vw1,wt,tile);
}

// ---- K6: y_init partials: PARTB[block][b][j] (bf16), no atomics ----
template<int CLEN>
__device__ __forceinline__ void yloop(const u16* __restrict__ wp, const float* __restrict__ sSb,
                                      float (&acc)[8][2]){
  #pragma unroll 10
  for (int c = 0; c < CLEN; ++c){
    u32 w = *(const u32*)(wp + (size_t)c*128);            // global, 256 B/wave, L1-shared
    float w0 = bfv((u16)(w & 0xffffu)), w1 = bfv((u16)(w >> 16));
    const float4* s4 = (const float4*)(sSb + c*32);       // LDS broadcast (free)
    float4 sa = s4[0], sb = s4[1];
    float sv[8] = {sa.x,sa.y,sa.z,sa.w,sb.x,sb.y,sb.z,sb.w};
    #pragma unroll
    for (int bb = 0; bb < 8; ++bb){
      acc[bb][0] += sv[bb]*w0;
      acc[bb][1] += sv[bb]*w1;
    }
  }
}
__global__ __launch_bounds__(256) void k_yinit(const u16* __restrict__ ST0T, const u16* __restrict__ wt,
                                               u16* __restrict__ PARTB){
  __shared__ float sS[130*32];   // 16.6 KB -> high occupancy
  int p = blockIdx.x >> 2, cq = blockIdx.x & 3;
  int c0 = cq*130;
  int clen = (cq == 3) ? 127 : 130;
  const ushort4* ssrc = (const ushort4*)(ST0T + ((size_t)p*MAPD + c0)*32);
  int n4 = clen*8;
  for (int i = threadIdx.x; i < n4; i += 256){
    ushort4 u = ssrc[i];
    float4 f; f.x = bfv(u.x); f.y = bfv(u.y); f.z = bfv(u.z); f.w = bfv(u.w);
    *(float4*)(sS + i*4) = f;
  }
  __syncthreads();
  int jg = threadIdx.x & 63, bg = threadIdx.x >> 6;
  int j0 = jg*2, b0 = bg*8;
  const u16* wp = wt + ((size_t)p*MAPD + c0)*128 + j0;
  float acc[8][2] = {};
  if (cq < 3) yloop<130>(wp, sS + b0, acc);
  else        yloop<127>(wp, sS + b0, acc);
  u32* op = (u32*)(PARTB + (size_t)blockIdx.x*4096);
  #pragma unroll
  for (int bb = 0; bb < 8; ++bb){
    u32 pk = (u32)fbf(acc[bb][0]) | ((u32)fbf(acc[bb][1]) << 16);
    op[((b0+bb)*128 + j0) >> 1] = pk;
  }
}

// ---- K6b: reduce 1024 partials -> YI (fp32) ----
__global__ __launch_bounds__(256) void k_yred(const u16* __restrict__ PARTB, float* __restrict__ YI){
  int o = blockIdx.x*64 + (threadIdx.x & 63);
  int kq = threadIdx.x >> 6;
  float s = 0.f;
  const u16* pp = PARTB + (size_t)kq*256*4096 + o;
  #pragma unroll 8
  for (int k = 0; k < 256; ++k) s += bfv(pp[(size_t)k*4096]);
  __shared__ float red[256];
  red[threadIdx.x] = s;
  __syncthreads();
  if (threadIdx.x < 64)
    YI[o] = red[threadIdx.x] + red[threadIdx.x+64] + red[threadIdx.x+128] + red[threadIdx.x+192];
}

// ---- K7: delta partial dots; grid (n x 4 c-chunks), j-paired u32 loads,
//      block's two waves split the c-chunk -> DLT8[(n*4+cq)*2+half][j] ----
__global__ __launch_bounds__(128) void k_delta(const float* __restrict__ H, const u16* __restrict__ wt,
                                               const u16* __restrict__ st0t,
                                               const int* __restrict__ pos, const void* done,
                                               const int* __restrict__ prev, const float* __restrict__ coef,
                                               float* __restrict__ dlt8, const int* flag){
  __shared__ float diff[132];
  bool f32 = (*flag != 0);
  int n = blockIdx.x >> 2, cq = blockIdx.x & 3;
  int c0 = cq*130, clen = (cq == 3) ? 127 : 130;
  int b = n & 31;
  int p = pos[n*2]*16 + pos[n*2+1];
  float dn = f32 ? ((const float*)done)[n] : bfv(((const u16*)done)[n]);
  float m = 1.f - dn;
  int pv = prev[n];
  float cf = coef[n]*m;
  const float* hc = H + (size_t)n*MAPD + c0;
  for (int c = threadIdx.x; c < clen; c += 128){
    float old;
    if (pv >= 0) old = H[(size_t)(pv*32 + b)*MAPD + c0 + c];
    else         old = bfv(st0t[((size_t)p*MAPD + c0 + c)*32 + b]);
    diff[c] = hc[c] - cf*old;
  }
  __syncthreads();
  int half = threadIdx.x >> 6, jp = threadIdx.x & 63, j0 = jp*2;
  int hbase, hlen;
  if (cq == 3){ hbase = half*64; hlen = half ? 63 : 64; }
  else        { hbase = half*65; hlen = 65; }
  const u16* wp = wt + ((size_t)p*MAPD + c0 + hbase)*128 + j0;
  const float* dptr = diff + hbase;
  float a0 = 0.f, a1 = 0.f;
  int c = 0;
  for (; c + 4 <= hlen; c += 4){
    u32 w0 = *(const u32*)(wp + (size_t)(c+0)*128);
    u32 w1 = *(const u32*)(wp + (size_t)(c+1)*128);
    u32 w2 = *(const u32*)(wp + (size_t)(c+2)*128);
    u32 w3 = *(const u32*)(wp + (size_t)(c+3)*128);
    float d0 = dptr[c], d1 = dptr[c+1], d2 = dptr[c+2], d3 = dptr[c+3];
    a0 += d0*bfv((u16)(w0 & 0xffffu)) + d1*bfv((u16)(w1 & 0xffffu))
        + d2*bfv((u16)(w2 & 0xffffu)) + d3*bfv((u16)(w3 & 0xffffu));
    a1 += d0*bfv((u16)(w0 >> 16)) + d1*bfv((u16)(w1 >> 16))
        + d2*bfv((u16)(w2 >> 16)) + d3*bfv((u16)(w3 >> 16));
  }
  for (; c < hlen; ++c){
    u32 w = *(const u32*)(wp + (size_t)c*128);
    a0 += dptr[c]*bfv((u16)(w & 0xffffu));
    a1 += dptr[c]*bfv((u16)(w >> 16));
  }
  f32x2 st; st[0] = a0; st[1] = a1;
  *(f32x2*)(dlt8 + ((size_t)blockIdx.x*2 + half)*128 + j0) = st;
}

// ---- K8a: barrier-free 32-step scan -> TH[n][128] fp32 ----
__global__ __launch_bounds__(128) void k_scan(const float* __restrict__ yi,
                                              const float* __restrict__ dlt8, const void* done,
                                              const void* pb1, const void* vb1,
                                              float* __restrict__ TH, const int* flag){
  bool f32 = (*flag != 0);
  int b = blockIdx.x, j = threadIdx.x;
  float y = yi[b*128 + j];
  float bias = (j < 64) ? (f32 ? ((const float*)pb1)[j]    : bfv(((const u16*)pb1)[j]))
                        : (f32 ? ((const float*)vb1)[j-64] : bfv(((const u16*)vb1)[j-64]));
  for (int t = 0; t < T_; ++t){
    int n = t*32 + b;
    float m = 1.f - (f32 ? ((const float*)done)[n] : bfv(((const u16*)done)[n]));
    const float* dp = dlt8 + (size_t)n*1024 + j;
    float d = dp[0] + dp[128] + dp[256] + dp[384]
            + dp[512] + dp[640] + dp[768] + dp[896];
    y = m*y + d;
    TH[(size_t)n*128 + j] = tanhf(y + bias);
  }
}

// ---- K8b: head matvecs from TH (wave per sample, shuffle reduce) ----
__global__ __launch_bounds__(256) void k_heads(const float* __restrict__ TH,
                                               const void* pw2, const void* pb2,
                                               const void* vw2, const void* vb2,
                                               void* out, const int* flag){
  bool f32 = (*flag != 0);
  int wv = threadIdx.x >> 6, lane = threadIdx.x & 63;
  int n = blockIdx.x*4 + wv;
  const float* th = TH + (size_t)n*128;
  float tq = th[lane];
  float tv = th[64 + lane];
  float acc[6];
  #pragma unroll
  for (int j = 0; j < 5; ++j)
    acc[j] = tq * (f32 ? ((const float*)pw2)[j*64 + lane] : bfv(((const u16*)pw2)[j*64 + lane]));
  acc[5] = tv * (f32 ? ((const float*)vw2)[lane] : bfv(((const u16*)vw2)[lane]));
  #pragma unroll
  for (int off = 32; off > 0; off >>= 1)
    #pragma unroll
    for (int j = 0; j < 6; ++j)
      acc[j] += __shfl_down(acc[j], off, 64);
  if (lane == 0){
    #pragma unroll
    for (int j = 0; j < 5; ++j){
      float s = acc[j] + (f32 ? ((const float*)pb2)[j] : bfv(((const u16*)pb2)[j]));
      if (f32) ((float*)out)[n*5 + j] = s; else ((u16*)out)[n*5 + j] = fbf(s);
    }
    float s = acc[5] + (f32 ? ((const float*)vb2)[0] : bfv(((const u16*)vb2)[0]));
    if (f32) ((float*)out)[5120 + n] = s; else ((u16*)out)[5120 + n] = fbf(s);
  }
}

// ---- K9: final_state closed form ----
template<bool F32> __device__ void final_body(const float* H, const void* st0,
                                              const int* lastw, const float* lastc, void* out){
  size_t i = (size_t)blockIdx.x*256 + threadIdx.x;
  if (i >= (size_t)B_*FLATD) return;
  int b = (int)(i / FLATD);
  int r = (int)(i - (size_t)b*FLATD);
  int c = r >> 8, p = r & 255;
  int lw = lastw[b*256 + p];
  float lc = lastc[b*256 + p];
  float v;
  if (lw >= 0) v = H[(size_t)(lw*32 + b)*MAPD + c]*lc;
  else         v = ld<F32>(st0, i)*lc;
  if constexpr (F32) ((float*)out)[6144 + i] = v; else ((u16*)out)[6144 + i] = fbf(v);
}
__global__ __launch_bounds__(256) void k_final(const float* H, const void* st0,
                                               const int* lastw, const float* lastc, void* out,
                                               const int* flag){
  if (*flag) final_body<true>(H,st0,lastw,lastc,out); else final_body<false>(H,st0,lastw,lastc,out);
}

extern "C" void kernel_launch(void* const* d_in, const int* in_sizes, int n_in,
                              void* d_out, int out_size, void* d_ws, size_t ws_size,
                              hipStream_t stream) {
  (void)in_sizes; (void)n_in; (void)out_size; (void)ws_size;
  const void* image = d_in[0];
  const int*  lact  = (const int*)d_in[1];
  const int*  pos   = (const int*)d_in[2];
  const void* done  = d_in[3];
  const void* st0   = d_in[4];
  const void* c1w = d_in[5];  const void* c1b = d_in[6];
  const void* c2w = d_in[7];  const void* c2b = d_in[8];
  const void* c3w = d_in[9];  const void* c3b = d_in[10];
  const void* fcw = d_in[11]; const void* fcb = d_in[12];
  const void* pw1 = d_in[13]; const void* pb1 = d_in[14];
  const void* pw2 = d_in[15]; const void* pb2 = d_in[16];
  const void* vw1 = d_in[17]; const void* vb1 = d_in[18];
  const void* vw2 = d_in[19]; const void* vb2 = d_in[20];
  char* ws = (char*)d_ws;

  // workspace (~54.7 MB). WT overlays C; DLT8 overlays PARTB (dead after k_yred).
  u16*   WT    = (u16*)  (ws + 0);           // 33,882,112
  u16*   C     = (u16*)  (ws + 19464192);    // 2,097,152 (overlays WT tail region used later)
  float* H     = (float*)(ws + 33882368);    // 2,117,632
  float* YI    = (float*)(ws + 36000256);    // 16,384
  u16*   PARTB = (u16*)  (ws + 36016640);    // 8,388,608 (1024*4096 bf16)
  float* DLT8  = (float*)(ws + 36016640);    // 4,194,304 (overlays PARTB, used after yred)
  int*   PREV  = (int*)  (ws + 44405248);
  float* COEF  = (float*)(ws + 44409344);
  int*   LASTW = (int*)  (ws + 44413440);
  float* LASTC = (float*)(ws + 44446208);
  int*   FLAG  = (int*)  (ws + 44478976);
  u16*   W1F   = (u16*)  (ws + 44479232);    // 12,288
  u16*   W2F   = (u16*)  (ws + 44491520);    // 65,536
  u16*   W3F   = (u16*)  (ws + 44557056);    // 73,728
  u16*   FWF   = (u16*)  (ws + 44630784);    // 1,048,576 (MFMA B-frags of fcw)
  u16*   ST0T  = (u16*)  (ws + 45679360);    // 8,470,528
  float* TH    = (float*)(ws + 54149888);    // 524,288 -> 54,674,176

  k_probe<<<1, 64, 0, stream>>>(image, FLAG);
  k_prep <<<684, 256, 0, stream>>>(c1w, c2w, c3w, fcw, st0, W1F, W2F, W3F, FWF, ST0T, FLAG);
  k_meta <<<36, 256, 0, stream>>>(pos, done, lact, PREV, COEF, H, LASTW, LASTC, FLAG);
  k_conv123<<<1024, 256, 0, stream>>>(image, W1F, c1b, W2F, c2b, W3F, c3b, C, FLAG);
  k_fc   <<<512, 256, 0, stream>>>(C, FWF, fcb, H, FLAG);
  k_wt   <<<1034, 256, 0, stream>>>(pw1, vw1, WT, FLAG);
  k_yinit<<<1024, 256, 0, stream>>>(ST0T, WT, PARTB);
  k_yred <<<64, 256, 0, stream>>>(PARTB, YI);
  k_delta<<<4096, 128, 0, stream>>>(H, WT, ST0T, pos, done, PREV, COEF, DLT8, FLAG);
  k_scan <<<32, 128, 0, stream>>>(YI, DLT8, done, pb1, vb1, TH, FLAG);
  k_heads<<<256, 256, 0, stream>>>(TH, pw2, pb2, vw2, vb2, d_out, FLAG);
  k_final<<<16544, 256, 0, stream>>>(H, st0, LASTW, LASTC, d_out, FLAG);
}

// Round 6
// 352.965 us; speedup vs baseline: 1.0426x; 1.0168x over previous
//
#include <hip/hip_runtime.h>

#define T_ 32
#define B_ 32
#define MAPD 517
#define P_ 256
#define FLATD (MAPD*P_)   // 132352
#define TBN (T_*B_)       // 1024

typedef unsigned short u16;
typedef unsigned int u32;
typedef __attribute__((ext_vector_type(4))) short short4v;
typedef __attribute__((ext_vector_type(8))) short short8v;
typedef __attribute__((ext_vector_type(4))) float f32x4;
typedef __attribute__((ext_vector_type(2))) float f32x2;
typedef __attribute__((ext_vector_type(4))) u32 u32x4;

__device__ __forceinline__ float bfv(u16 u){ u32 x = ((u32)u)<<16; return __uint_as_float(x); }
__device__ __forceinline__ u16 fbf(float f){
  u32 x = __float_as_uint(f);
  return (u16)((x + 0x7fffu + ((x>>16)&1u))>>16);
}
template<bool F32> __device__ __forceinline__ float ld(const void* p, size_t i){
  if constexpr (F32) return ((const float*)p)[i];
  else               return bfv(((const u16*)p)[i]);
}
__device__ __forceinline__ float ldf(bool f32, const void* p, size_t i){
  return f32 ? ((const float*)p)[i] : bfv(((const u16*)p)[i]);
}

// ---- inline dtype probe (replaces k_probe kernel): per-wave, no barrier ----
__device__ __forceinline__ bool probe_f32(const void* img){
  int lane = threadIdx.x & 63;
  ushort4 v = ((const ushort4*)img)[lane];      // lanes cover first 256 u16
  int c = (v.x <= 0x4380u) + (v.y <= 0x4380u) + (v.z <= 0x4380u) + (v.w <= 0x4380u);
  #pragma unroll
  for (int off = 32; off > 0; off >>= 1) c += __shfl_xor(c, off, 64);
  return c < 240;
}

// ================= k_A: wt-transpose (1034) + prep (684) + meta (36) =================
template<bool F32> __device__ void wt_body(int lbid, const void* pw1, const void* vw1,
                                           u16* wt, u32* tile){
  int c  = lbid >> 1;
  int ph = lbid & 1;
  for (int it = 0; it < 4; ++it){
    int idx = it*256 + threadIdx.x;        // [0,1024)
    int jp = idx >> 4, pg = idx & 15;      // jp: 64 j-pairs, pg: 16 pp-groups of 8
    int j0 = jp*2;
    const void* w = (j0 < 64) ? pw1 : vw1;
    int jj0 = (j0 < 64) ? j0 : j0-64;
    size_t base0 = (size_t)jj0*FLATD + c*P_ + ph*128 + pg*8;
    size_t base1 = base0 + FLATD;
    u16 a[8], b[8];
    if constexpr (F32){
      const float* f = (const float*)w;
      float4 a0 = *(const float4*)(f + base0), a1 = *(const float4*)(f + base0 + 4);
      float4 b0 = *(const float4*)(f + base1), b1 = *(const float4*)(f + base1 + 4);
      a[0]=fbf(a0.x); a[1]=fbf(a0.y); a[2]=fbf(a0.z); a[3]=fbf(a0.w);
      a[4]=fbf(a1.x); a[5]=fbf(a1.y); a[6]=fbf(a1.z); a[7]=fbf(a1.w);
      b[0]=fbf(b0.x); b[1]=fbf(b0.y); b[2]=fbf(b0.z); b[3]=fbf(b0.w);
      b[4]=fbf(b1.x); b[5]=fbf(b1.y); b[6]=fbf(b1.z); b[7]=fbf(b1.w);
    } else {
      short8v va = *(const short8v*)((const u16*)w + base0);
      short8v vb = *(const short8v*)((const u16*)w + base1);
      #pragma unroll
      for (int k = 0; k < 8; ++k){ a[k] = (u16)va[k]; b[k] = (u16)vb[k]; }
    }
    int slot = (jp >> 2) ^ pg;
    int sub  = jp & 3;
    #pragma unroll
    for (int k = 0; k < 8; ++k){
      int pp = pg*8 + k;
      tile[pp*64 + slot*4 + sub] = (u32)a[k] | ((u32)b[k] << 16);
    }
  }
  __syncthreads();
  for (int it = 0; it < 8; ++it){
    int idx = it*256 + threadIdx.x;        // [0,2048)
    int pp = idx >> 4, jb = idx & 15;
    int slot = jb ^ ((pp >> 3) & 15);
    u32x4 v = *(const u32x4*)(tile + pp*64 + slot*4);
    int p = ph*128 + pp;
    *(u32x4*)(wt + ((size_t)p*MAPD + c)*128 + jb*8) = v;
  }
}

__device__ void prep_body(bool f32, int bid, const void* c1w, const void* c2w, const void* c3w,
                          const void* fcw, const void* st0,
                          u16* W1F, u16* W2F, u16* W3F, u16* FWF, u16* ST0T, char* smem_){
  int tid = threadIdx.x;
  if (bid < 24){
    int idx = bid*256 + tid;                   // 6144
    int j = idx & 7, l = (idx>>3) & 63, t = idx>>9;
    int nt = t/6, s = t - nt*6;
    int oc = nt*16 + (l&15);
    int kk = 8*(4*s + (l>>4)) + j;
    float v = ldf(f32, c1w, oc*192+kk);
    W1F[idx] = fbf(v);
  } else if (bid < 152){
    int idx = (bid-24)*256 + tid;              // 32768
    int j = idx & 7, l = (idx>>3) & 63, s = (idx>>9) & 15, nt = idx>>13;
    int oc = nt*16 + (l&15);
    int cin = (l>>4)*8 + j;
    int src = oc*512 + cin*16 + (s>>2)*4 + (s&3);
    W2F[idx] = fbf(ldf(f32, c2w, src));
  } else if (bid < 296){
    int idx = (bid-152)*256 + tid;             // 36864
    int j = idx & 7, l = (idx>>3) & 63, t = idx>>9;   // t = nt*18+s
    int nt = t/18, s = t - nt*18;
    int oc = nt*16 + (l&15);
    int c = (s&1)*32 + (l>>4)*8 + j;
    int src = oc*576 + c*9 + (s>>1);
    W3F[idx] = fbf(ldf(f32, c3w, src));
  } else if (bid < 424){
    // FWF: MFMA B-fragments of fc_w for fc GEMM.
    int b = bid - 296;                          // 128 blocks x 4096 elems
    for (int it = 0; it < 16; ++it){
      int idx = (b*16 + it)*256 + tid;          // 524288 total
      int j = idx & 7, l = (idx>>3) & 63, frag = idx >> 9;
      int nt = frag >> 5, kt = frag & 31;
      int kc = kt*32 + ((l>>4)<<3) + j;
      int kr = (kc & 63)*16 + (kc >> 6);
      int o  = nt*16 + (l & 15);
      FWF[idx] = fbf(ldf(f32, fcw, (size_t)o*1024 + kr));
    }
  } else {
    // ST0T[p][c][b] transpose
    u16* tile = (u16*)smem_;                   // 32,768 B
    int b0 = bid - 424;                        // 260 blocks
    int c0 = (b0 >> 2)*8, p0 = (b0 & 3)*64;
    for (int it = 0; it < 64; ++it){
      int idx = it*256 + tid;
      int pl = idx & 63, b = (idx>>6)&31, ci = idx>>11;
      int c = c0 + ci;
      float v = 0.f;
      if (c < MAPD) v = ldf(f32, st0, ((size_t)b*MAPD+c)*256 + p0+pl);
      tile[ci*2048 + pl*32 + b] = fbf(v);
    }
    __syncthreads();
    for (int it = 0; it < 64; ++it){
      int idx = it*256 + tid;
      int b = idx & 31, ci = (idx>>5)&7, pl = idx>>8;
      int c = c0 + ci;
      if (c < MAPD)
        ST0T[((size_t)(p0+pl)*MAPD + c)*32 + b] = tile[ci*2048 + pl*32 + b];
    }
  }
}

__device__ void meta_body(bool f32, int bid, const int* pos, const void* done, const int* lact,
                          int* prev, float* coef, float* H, int* lastw, float* lastc){
  if (bid < 4){
    int i = bid*256 + threadIdx.x;
    int t = i >> 5, b = i & 31;
    int p = pos[i*2]*16 + pos[i*2+1];
    int pv = -1;
    for (int s = t-1; s >= 0; --s){
      int n = s*32 + b;
      if (pos[n*2]*16 + pos[n*2+1] == p){ pv = s; break; }
    }
    float cf = 1.f;
    for (int s = (pv<0?0:pv+1); s <= t-1; ++s)
      cf *= (1.f - ldf(f32, done, s*32+b));
    prev[i] = pv; coef[i] = cf;
    int la = lact[i];
    #pragma unroll
    for (int a = 0; a < 5; ++a) H[(size_t)i*MAPD + 512 + a] = (la == a) ? 1.f : 0.f;
  } else {
    int i = (bid-4)*256 + threadIdx.x;
    int b = i >> 8, p = i & 255;
    int lw = -1;
    for (int s = T_-1; s >= 0; --s){
      int n = s*32 + b;
      if (pos[n*2]*16 + pos[n*2+1] == p){ lw = s; break; }
    }
    float cf = 1.f;
    for (int s = (lw<0?0:lw+1); s < T_; ++s)
      cf *= (1.f - ldf(f32, done, s*32+b));
    lastw[i] = lw; lastc[i] = cf;
  }
}

__global__ __launch_bounds__(256) void k_A(const void* image,
                                           const void* pw1, const void* vw1, u16* wt,
                                           const void* c1w, const void* c2w, const void* c3w,
                                           const void* fcw, const void* st0,
                                           u16* W1F, u16* W2F, u16* W3F, u16* FWF, u16* ST0T,
                                           const int* pos, const void* done, const int* lact,
                                           int* prev, float* coef, float* H, int* lastw, float* lastc){
  __shared__ __align__(16) char smem_[32768];
  bool f32 = probe_f32(image);
  int bid = blockIdx.x;
  if (bid < 1034){
    if (f32) wt_body<true>(bid, pw1, vw1, wt, (u32*)smem_);
    else     wt_body<false>(bid, pw1, vw1, wt, (u32*)smem_);
  } else if (bid < 1718){
    prep_body(f32, bid-1034, c1w, c2w, c3w, fcw, st0, W1F, W2F, W3F, FWF, ST0T, smem_);
  } else {
    meta_body(f32, bid-1718, pos, done, lact, prev, coef, H, lastw, lastc);
  }
}

// ================= k_conv123: fused convs (R4 body, best measured) =================
__global__ __launch_bounds__(256) void k_conv123(const void* img,
                                                 const u16* __restrict__ W1F, const void* b1,
                                                 const u16* __restrict__ W2F, const void* b2,
                                                 const u16* __restrict__ W3F, const void* b3,
                                                 u16* __restrict__ out){
  __shared__ __align__(16) u16 smem[19488];
  u16* sImg = smem;            // 12288 u16
  u16* sA   = smem + 12288;    // 7200 u16
  u16* sBv  = smem;            // 2304 u16, overlays sImg after conv1
  bool f32 = probe_f32(img);
  int n = blockIdx.x, tid = threadIdx.x;
  if (f32){
    const float4* ip = (const float4*)((const float*)img + (size_t)n*12288);
    for (int i = tid; i < 3072; i += 256){
      float4 v = ip[i];
      ushort4 u; u.x = fbf(v.x); u.y = fbf(v.y); u.z = fbf(v.z); u.w = fbf(v.w);
      int L = i*4;
      int addr = (L & ~63) | (((L & 63) + (((L >> 6) & 3) << 4)) & 63);
      *(ushort4*)(sImg + addr) = u;
    }
  } else {
    const ushort4* ip = (const ushort4*)((const u16*)img + (size_t)n*12288);
    for (int i = tid; i < 3072; i += 256){
      ushort4 u = ip[i];
      int L = i*4;
      int addr = (L & ~63) | (((L & 63) + (((L >> 6) & 3) << 4)) & 63);
      *(ushort4*)(sImg + addr) = u;
    }
  }
  int wv = tid >> 6, lane = tid & 63;
  int mi = lane & 15, q = lane >> 4;

  short8v bfr1[2][6];
  #pragma unroll
  for (int nt = 0; nt < 2; ++nt)
    #pragma unroll
    for (int s = 0; s < 6; ++s)
      bfr1[nt][s] = ((const short8v*)W1F)[(nt*6+s)*64 + lane];
  float b1v[2];
  #pragma unroll
  for (int nt = 0; nt < 2; ++nt)
    b1v[nt] = ldf(f32, b1, nt*16+mi);
  __syncthreads();

  {
    f32x4 acc[4][2];
    #pragma unroll
    for (int mt = 0; mt < 4; ++mt)
      #pragma unroll
      for (int nt = 0; nt < 2; ++nt)
        acc[mt][nt] = (f32x4){0.f,0.f,0.f,0.f};
    int base[4];
    #pragma unroll
    for (int mt = 0; mt < 4; ++mt){
      int m = (wv*4+mt)*16 + mi;
      int mc = m < 225 ? m : 224;
      int oy = mc/15, ox = mc - oy*15;
      base[mt] = oy*256 + ox*4;
    }
    for (int s = 0; s < 6; ++s){
      int cky = 4*s + q;
      int off = (cky >> 3)*4096 + (cky & 7)*64;
      #pragma unroll
      for (int mt = 0; mt < 4; ++mt){
        int Lb = base[mt] + off;
        const u16* rp = sImg + (Lb & ~63);
        int x0 = Lb & 63;
        int rot = ((Lb >> 6) & 3) << 4;
        short4v lo = *(const short4v*)(rp + ((x0 + rot) & 63));
        short4v hi = *(const short4v*)(rp + ((x0 + 4 + rot) & 63));
        short8v a = __builtin_shufflevector(lo, hi, 0,1,2,3,4,5,6,7);
        acc[mt][0] = __builtin_amdgcn_mfma_f32_16x16x32_bf16(a, bfr1[0][s], acc[mt][0], 0,0,0);
        acc[mt][1] = __builtin_amdgcn_mfma_f32_16x16x32_bf16(a, bfr1[1][s], acc[mt][1], 0,0,0);
      }
    }
    __syncthreads();   // sImg reads done before sBv (alias) writes in conv2
    #pragma unroll
    for (int mt = 0; mt < 4; ++mt){
      int mrow0 = (wv*4+mt)*16 + q*4;
      #pragma unroll
      for (int nt = 0; nt < 2; ++nt){
        int oc = nt*16 + mi;
        #pragma unroll
        for (int r = 0; r < 4; ++r){
          int m = mrow0 + r;
          if (m < 225){
            int g = ((oc >> 3) ^ ((m >> 1) & 3)) << 3;
            sA[m*32 + g + (oc & 7)] = fbf(fmaxf(acc[mt][nt][r] + b1v[nt], 0.f));
          }
        }
      }
    }
  }
  __syncthreads();

  {
    short8v bfr2[16];
    #pragma unroll
    for (int s = 0; s < 16; ++s)
      bfr2[s] = ((const short8v*)W2F)[(wv*16+s)*64 + lane];
    int oc = wv*16 + mi;
    float bv = ldf(f32, b2, oc);
    f32x4 acc[3];
    #pragma unroll
    for (int mt = 0; mt < 3; ++mt) acc[mt] = (f32x4){0.f,0.f,0.f,0.f};
    int pixb[3];
    #pragma unroll
    for (int mt = 0; mt < 3; ++mt){
      int m = mt*16 + mi; if (m > 35) m = 35;
      int oy = m/6, ox = m - oy*6;
      pixb[mt] = oy*30 + ox*2;
    }
    #pragma unroll
    for (int s = 0; s < 16; ++s){
      int dp = (s>>2)*15 + (s&3);
      #pragma unroll
      for (int mt = 0; mt < 3; ++mt){
        int pix = pixb[mt] + dp;
        int g = (q ^ ((pix >> 1) & 3)) << 3;
        short8v a = *(const short8v*)(sA + pix*32 + g);
        acc[mt] = __builtin_amdgcn_mfma_f32_16x16x32_bf16(a, bfr2[s], acc[mt], 0,0,0);
      }
    }
    __syncthreads();
    #pragma unroll
    for (int mt = 0; mt < 3; ++mt)
      #pragma unroll
      for (int r = 0; r < 4; ++r){
        int m = mt*16 + q*4 + r;
        if (m < 36){
          int g = ((oc >> 3) ^ (m & 7)) << 3;
          sBv[m*64 + g + (oc & 7)] = fbf(fmaxf(acc[mt][r] + bv, 0.f));
        }
      }
  }
  __syncthreads();

  {
    int oy = mi >> 2, ox = mi & 3;
    int oc = wv*16 + mi;
    float bv = ldf(f32, b3, oc);
    short8v bfr3[18];
    #pragma unroll
    for (int s = 0; s < 18; ++s)
      bfr3[s] = ((const short8v*)W3F)[(wv*18+s)*64 + lane];
    f32x4 acc = (f32x4){0.f,0.f,0.f,0.f};
    #pragma unroll
    for (int s = 0; s < 18; ++s){
      int pair = s >> 1, ky = pair/3, kx = pair - ky*3;
      int pix = (oy+ky)*6 + ox+kx;
      int g = ((((s & 1) << 2) | q) ^ (pix & 7)) << 3;
      short8v a = *(const short8v*)(sBv + pix*64 + g);
      acc = __builtin_amdgcn_mfma_f32_16x16x32_bf16(a, bfr3[s], acc, 0,0,0);
    }
    u16* ob = out + (size_t)n*1024;
    #pragma unroll
    for (int r = 0; r < 4; ++r)
      ob[(q*4+r)*64 + oc] = fbf(fmaxf(acc[r] + bv, 0.f));
  }
}

// ================= k_C: yinit (1024) + fc (512) =================
template<int CLEN>
__device__ __forceinline__ void yloop(const u16* __restrict__ wp, const float* __restrict__ sSb,
                                      float (&acc)[8][2]){
  #pragma unroll 10
  for (int c = 0; c < CLEN; ++c){
    u32 w = *(const u32*)(wp + (size_t)c*128);
    float w0 = bfv((u16)(w & 0xffffu)), w1 = bfv((u16)(w >> 16));
    const float4* s4 = (const float4*)(sSb + c*32);
    float4 sa = s4[0], sb = s4[1];
    float sv[8] = {sa.x,sa.y,sa.z,sa.w,sb.x,sb.y,sb.z,sb.w};
    #pragma unroll
    for (int bb = 0; bb < 8; ++bb){
      acc[bb][0] += sv[bb]*w0;
      acc[bb][1] += sv[bb]*w1;
    }
  }
}
__device__ void yinit_body(int lbid, const u16* __restrict__ ST0T, const u16* __restrict__ wt,
                           u16* __restrict__ PARTB, float* sS){
  int p = lbid >> 2, cq = lbid & 3;
  int c0 = cq*130;
  int clen = (cq == 3) ? 127 : 130;
  const ushort4* ssrc = (const ushort4*)(ST0T + ((size_t)p*MAPD + c0)*32);
  int n4 = clen*8;
  for (int i = threadIdx.x; i < n4; i += 256){
    ushort4 u = ssrc[i];
    float4 f; f.x = bfv(u.x); f.y = bfv(u.y); f.z = bfv(u.z); f.w = bfv(u.w);
    *(float4*)(sS + i*4) = f;
  }
  __syncthreads();
  int jg = threadIdx.x & 63, bg = threadIdx.x >> 6;
  int j0 = jg*2, b0 = bg*8;
  const u16* wp = wt + ((size_t)p*MAPD + c0)*128 + j0;
  float acc[8][2] = {};
  if (cq < 3) yloop<130>(wp, sS + b0, acc);
  else        yloop<127>(wp, sS + b0, acc);
  u32* op = (u32*)(PARTB + (size_t)lbid*4096);
  #pragma unroll
  for (int bb = 0; bb < 8; ++bb){
    u32 pk = (u32)fbf(acc[bb][0]) | ((u32)fbf(acc[bb][1]) << 16);
    op[((b0+bb)*128 + j0) >> 1] = pk;
  }
}
__device__ void fc_body(int lbid, bool f32, const u16* __restrict__ C, const u16* __restrict__ FWF,
                        const void* fb, float* __restrict__ H){
  int wv = threadIdx.x >> 6, lane = threadIdx.x & 63;
  int mi = lane & 15, q = lane >> 4;
  int mt = lbid >> 3;               // 0..63
  int nt = (lbid & 7)*4 + wv;       // 0..31
  const u16* ap = C + (size_t)(mt*16 + mi)*1024 + q*8;
  const short8v* bp = (const short8v*)FWF + (size_t)nt*32*64 + lane;
  f32x4 acc0 = (f32x4){0.f,0.f,0.f,0.f};
  f32x4 acc1 = (f32x4){0.f,0.f,0.f,0.f};
  #pragma unroll
  for (int kt = 0; kt < 32; kt += 2){
    short8v a0 = *(const short8v*)(ap + kt*32);
    short8v b0 = bp[kt*64];
    short8v a1 = *(const short8v*)(ap + (kt+1)*32);
    short8v b1 = bp[(kt+1)*64];
    acc0 = __builtin_amdgcn_mfma_f32_16x16x32_bf16(a0, b0, acc0, 0,0,0);
    acc1 = __builtin_amdgcn_mfma_f32_16x16x32_bf16(a1, b1, acc1, 0,0,0);
  }
  int o = nt*16 + mi;
  float bv = ldf(f32, fb, o);
  #pragma unroll
  for (int r = 0; r < 4; ++r){
    int m = mt*16 + q*4 + r;
    H[(size_t)m*MAPD + o] = fmaxf(acc0[r] + acc1[r] + bv, 0.f);
  }
}
__global__ __launch_bounds__(256) void k_C(const void* image,
                                           const u16* __restrict__ ST0T, const u16* __restrict__ wt,
                                           u16* __restrict__ PARTB,
                                           const u16* __restrict__ C, const u16* __restrict__ FWF,
                                           const void* fb, float* __restrict__ H){
  __shared__ float sS[130*32];   // 16.6 KB (yinit branch)
  if (blockIdx.x < 1024){
    yinit_body(blockIdx.x, ST0T, wt, PARTB, sS);
  } else {
    bool f32 = probe_f32(image);
    fc_body(blockIdx.x - 1024, f32, C, FWF, fb, H);
  }
}

// ================= k_D: delta (2048 blocks x 2 units) + yred (64) =================
__device__ void delta_body(int obid, int ltid, float* diff, bool f32,
                           const float* __restrict__ H, const u16* __restrict__ wt,
                           const u16* __restrict__ st0t,
                           const int* __restrict__ pos, const void* done,
                           const int* __restrict__ prev, const float* __restrict__ coef,
                           float* __restrict__ dlt8){
  int n = obid >> 2, cq = obid & 3;
  int c0 = cq*130, clen = (cq == 3) ? 127 : 130;
  int b = n & 31;
  int p = pos[n*2]*16 + pos[n*2+1];
  float dn = ldf(f32, done, n);
  float m = 1.f - dn;
  int pv = prev[n];
  float cf = coef[n]*m;
  const float* hc = H + (size_t)n*MAPD + c0;
  for (int c = ltid; c < clen; c += 128){
    float old;
    if (pv >= 0) old = H[(size_t)(pv*32 + b)*MAPD + c0 + c];
    else         old = bfv(st0t[((size_t)p*MAPD + c0 + c)*32 + b]);
    diff[c] = hc[c] - cf*old;
  }
  __syncthreads();
  int half = ltid >> 6, jp = ltid & 63, j0 = jp*2;
  int hbase, hlen;
  if (cq == 3){ hbase = half*64; hlen = half ? 63 : 64; }
  else        { hbase = half*65; hlen = 65; }
  const u16* wp = wt + ((size_t)p*MAPD + c0 + hbase)*128 + j0;
  const float* dptr = diff + hbase;
  float a0 = 0.f, a1 = 0.f;
  int c = 0;
  for (; c + 4 <= hlen; c += 4){
    u32 w0 = *(const u32*)(wp + (size_t)(c+0)*128);
    u32 w1 = *(const u32*)(wp + (size_t)(c+1)*128);
    u32 w2 = *(const u32*)(wp + (size_t)(c+2)*128);
    u32 w3 = *(const u32*)(wp + (size_t)(c+3)*128);
    float d0 = dptr[c], d1 = dptr[c+1], d2 = dptr[c+2], d3 = dptr[c+3];
    a0 += d0*bfv((u16)(w0 & 0xffffu)) + d1*bfv((u16)(w1 & 0xffffu))
        + d2*bfv((u16)(w2 & 0xffffu)) + d3*bfv((u16)(w3 & 0xffffu));
    a1 += d0*bfv((u16)(w0 >> 16)) + d1*bfv((u16)(w1 >> 16))
        + d2*bfv((u16)(w2 >> 16)) + d3*bfv((u16)(w3 >> 16));
  }
  for (; c < hlen; ++c){
    u32 w = *(const u32*)(wp + (size_t)c*128);
    a0 += dptr[c]*bfv((u16)(w & 0xffffu));
    a1 += dptr[c]*bfv((u16)(w >> 16));
  }
  f32x2 st; st[0] = a0; st[1] = a1;
  *(f32x2*)(dlt8 + ((size_t)obid*2 + half)*128 + j0) = st;
}
__global__ __launch_bounds__(256) void k_D(const void* image,
                                           const float* __restrict__ H, const u16* __restrict__ wt,
                                           const u16* __restrict__ st0t,
                                           const int* __restrict__ pos, const void* done,
                                           const int* __restrict__ prev, const float* __restrict__ coef,
                                           float* __restrict__ dlt8,
                                           const u16* __restrict__ PARTB, float* __restrict__ YI){
  __shared__ float diff2[2][132];
  __shared__ float red[256];
  if (blockIdx.x < 2048){
    bool f32 = probe_f32(image);
    int sub = threadIdx.x >> 7;
    int obid = blockIdx.x*2 + sub;
    delta_body(obid, threadIdx.x & 127, diff2[sub], f32, H, wt, st0t, pos, done, prev, coef, dlt8);
  } else {
    int lbid = blockIdx.x - 2048;
    int o = lbid*64 + (threadIdx.x & 63);
    int kq = threadIdx.x >> 6;
    float s = 0.f;
    const u16* pp = PARTB + (size_t)kq*256*4096 + o;
    #pragma unroll 8
    for (int k = 0; k < 256; ++k) s += bfv(pp[(size_t)k*4096]);
    red[threadIdx.x] = s;
    __syncthreads();
    if (threadIdx.x < 64)
      YI[o] = red[threadIdx.x] + red[threadIdx.x+64] + red[threadIdx.x+128] + red[threadIdx.x+192];
  }
}

// ================= k_E: scan+heads (32) + final (16544) =================
__device__ void scan_heads_body(bool f32, const float* __restrict__ yi,
                                const float* __restrict__ dlt8, const void* done,
                                const void* pb1, const void* vb1,
                                const void* pw2, const void* pb2,
                                const void* vw2, const void* vb2, void* out){
  int b = blockIdx.x, j = threadIdx.x;       // j in [0,128)
  int lane = j & 63;
  bool pol = j < 64;
  float y = yi[b*128 + j];
  float bias = pol ? ldf(f32, pb1, j) : ldf(f32, vb1, j-64);
  float w2[5];
  if (pol){
    #pragma unroll
    for (int jj = 0; jj < 5; ++jj) w2[jj] = ldf(f32, pw2, jj*64 + lane);
  } else {
    w2[0] = ldf(f32, vw2, lane);
  }
  for (int t = 0; t < T_; ++t){
    int n = t*32 + b;
    float m = 1.f - ldf(f32, done, n);
    const float* dp = dlt8 + (size_t)n*1024 + j;
    float d = dp[0] + dp[128] + dp[256] + dp[384]
            + dp[512] + dp[640] + dp[768] + dp[896];
    y = m*y + d;
    float th = tanhf(y + bias);
    if (pol){
      float s0 = th*w2[0], s1 = th*w2[1], s2 = th*w2[2], s3 = th*w2[3], s4 = th*w2[4];
      #pragma unroll
      for (int off = 32; off > 0; off >>= 1){
        s0 += __shfl_xor(s0, off, 64);
        s1 += __shfl_xor(s1, off, 64);
        s2 += __shfl_xor(s2, off, 64);
        s3 += __shfl_xor(s3, off, 64);
        s4 += __shfl_xor(s4, off, 64);
      }
      if (lane == 0){
        float sv[5] = {s0,s1,s2,s3,s4};
        #pragma unroll
        for (int jj = 0; jj < 5; ++jj){
          float s = sv[jj] + ldf(f32, pb2, jj);
          if (f32) ((float*)out)[n*5 + jj] = s; else ((u16*)out)[n*5 + jj] = fbf(s);
        }
      }
    } else {
      float s = th*w2[0];
      #pragma unroll
      for (int off = 32; off > 0; off >>= 1) s += __shfl_xor(s, off, 64);
      if (lane == 0){
        s += ldf(f32, vb2, 0);
        if (f32) ((float*)out)[5120 + n] = s; else ((u16*)out)[5120 + n] = fbf(s);
      }
    }
  }
}
__global__ __launch_bounds__(256) void k_E(const void* image,
                                           const float* __restrict__ yi, const float* __restrict__ dlt8,
                                           const void* done, const void* pb1, const void* vb1,
                                           const void* pw2, const void* pb2,
                                           const void* vw2, const void* vb2,
                                           const float* __restrict__ H, const void* st0,
                                           const int* __restrict__ lastw, const float* __restrict__ lastc,
                                           void* out){
  bool f32 = probe_f32(image);
  if (blockIdx.x < 32){
    if (threadIdx.x >= 128) return;
    scan_heads_body(f32, yi, dlt8, done, pb1, vb1, pw2, pb2, vw2, vb2, out);
  } else {
    size_t i = (size_t)(blockIdx.x - 32)*256 + threadIdx.x;
    if (i >= (size_t)B_*FLATD) return;
    int b = (int)(i / FLATD);
    int r = (int)(i - (size_t)b*FLATD);
    int c = r >> 8, p = r & 255;
    int lw = lastw[b*256 + p];
    float lc = lastc[b*256 + p];
    float v;
    if (lw >= 0) v = H[(size_t)(lw*32 + b)*MAPD + c]*lc;
    else         v = ldf(f32, st0, i)*lc;
    if (f32) ((float*)out)[6144 + i] = v; else ((u16*)out)[6144 + i] = fbf(v);
  }
}

extern "C" void kernel_launch(void* const* d_in, const int* in_sizes, int n_in,
                              void* d_out, int out_size, void* d_ws, size_t ws_size,
                              hipStream_t stream) {
  (void)in_sizes; (void)n_in; (void)out_size; (void)ws_size;
  const void* image = d_in[0];
  const int*  lact  = (const int*)d_in[1];
  const int*  pos   = (const int*)d_in[2];
  const void* done  = d_in[3];
  const void* st0   = d_in[4];
  const void* c1w = d_in[5];  const void* c1b = d_in[6];
  const void* c2w = d_in[7];  const void* c2b = d_in[8];
  const void* c3w = d_in[9];  const void* c3b = d_in[10];
  const void* fcw = d_in[11]; const void* fcb = d_in[12];
  const void* pw1 = d_in[13]; const void* pb1 = d_in[14];
  const void* pw2 = d_in[15]; const void* pb2 = d_in[16];
  const void* vw1 = d_in[17]; const void* vb1 = d_in[18];
  const void* vw2 = d_in[19]; const void* vb2 = d_in[20];
  char* ws = (char*)d_ws;

  // workspace (~60.5 MB). No live overlays: WT written in k_A (first), read through k_D;
  // C and DLT8 get their own regions.
  u16*   WT    = (u16*)  (ws + 0);           // 33,882,112
  float* H     = (float*)(ws + 33882368);    // 2,117,632
  float* YI    = (float*)(ws + 36000256);    // 16,384
  u16*   PARTB = (u16*)  (ws + 36016640);    // 8,388,608
  int*   PREV  = (int*)  (ws + 44405248);
  float* COEF  = (float*)(ws + 44409344);
  int*   LASTW = (int*)  (ws + 44413440);
  float* LASTC = (float*)(ws + 44446208);
  u16*   W1F   = (u16*)  (ws + 44479232);    // 12,288
  u16*   W2F   = (u16*)  (ws + 44491520);    // 65,536
  u16*   W3F   = (u16*)  (ws + 44557056);    // 73,728
  u16*   FWF   = (u16*)  (ws + 44630784);    // 1,048,576
  u16*   ST0T  = (u16*)  (ws + 45679360);    // 8,470,528 -> 54,149,888
  u16*   C     = (u16*)  (ws + 54149888);    // 2,097,152 -> 56,247,040
  float* DLT8  = (float*)(ws + 56247040);    // 4,194,304 -> 60,441,344

  // 5 launches (was 13): merged by dependency level.
  k_A      <<<1754, 256, 0, stream>>>(image, pw1, vw1, WT, c1w, c2w, c3w, fcw, st0,
                                      W1F, W2F, W3F, FWF, ST0T,
                                      pos, done, lact, PREV, COEF, H, LASTW, LASTC);
  k_conv123<<<1024, 256, 0, stream>>>(image, W1F, c1b, W2F, c2b, W3F, c3b, C);
  k_C      <<<1536, 256, 0, stream>>>(image, ST0T, WT, PARTB, C, FWF, fcb, H);
  k_D      <<<2112, 256, 0, stream>>>(image, H, WT, ST0T, pos, done, PREV, COEF, DLT8, PARTB, YI);
  k_E      <<<16576, 256, 0, stream>>>(image, YI, DLT8, done, pb1, vb1, pw2, pb2, vw2, vb2,
                                       H, st0, LASTW, LASTC, d_out);
}

// Round 7
// 326.716 us; speedup vs baseline: 1.1263x; 1.0803x over previous
//
#include <hip/hip_runtime.h>

#define T_ 32
#define B_ 32
#define MAPD 517
#define P_ 256
#define FLATD (MAPD*P_)   // 132352
#define TBN (T_*B_)       // 1024

typedef unsigned short u16;
typedef unsigned int u32;
typedef __attribute__((ext_vector_type(4))) short short4v;
typedef __attribute__((ext_vector_type(8))) short short8v;
typedef __attribute__((ext_vector_type(4))) float f32x4;
typedef __attribute__((ext_vector_type(2))) float f32x2;
typedef __attribute__((ext_vector_type(4))) u32 u32x4;

__device__ __forceinline__ float bfv(u16 u){ u32 x = ((u32)u)<<16; return __uint_as_float(x); }
__device__ __forceinline__ u16 fbf(float f){
  u32 x = __float_as_uint(f);
  return (u16)((x + 0x7fffu + ((x>>16)&1u))>>16);
}
template<bool F32> __device__ __forceinline__ float ld(const void* p, size_t i){
  if constexpr (F32) return ((const float*)p)[i];
  else               return bfv(((const u16*)p)[i]);
}
__device__ __forceinline__ float ldf(bool f32, const void* p, size_t i){
  return f32 ? ((const float*)p)[i] : bfv(((const u16*)p)[i]);
}

// ---- inline dtype probe: per-wave, no barrier ----
__device__ __forceinline__ bool probe_f32(const void* img){
  int lane = threadIdx.x & 63;
  ushort4 v = ((const ushort4*)img)[lane];      // lanes cover first 256 u16
  int c = (v.x <= 0x4380u) + (v.y <= 0x4380u) + (v.z <= 0x4380u) + (v.w <= 0x4380u);
  #pragma unroll
  for (int off = 32; off > 0; off >>= 1) c += __shfl_xor(c, off, 64);
  return c < 240;
}

// ================= k_A: wt-transpose (1034) + prep (684) + meta (36) =================
template<bool F32> __device__ void wt_body(int lbid, const void* pw1, const void* vw1,
                                           u16* wt, u32* tile){
  int c  = lbid >> 1;
  int ph = lbid & 1;
  for (int it = 0; it < 4; ++it){
    int idx = it*256 + threadIdx.x;        // [0,1024)
    int jp = idx >> 4, pg = idx & 15;      // jp: 64 j-pairs, pg: 16 pp-groups of 8
    int j0 = jp*2;
    const void* w = (j0 < 64) ? pw1 : vw1;
    int jj0 = (j0 < 64) ? j0 : j0-64;
    size_t base0 = (size_t)jj0*FLATD + c*P_ + ph*128 + pg*8;
    size_t base1 = base0 + FLATD;
    u16 a[8], b[8];
    if constexpr (F32){
      const float* f = (const float*)w;
      float4 a0 = *(const float4*)(f + base0), a1 = *(const float4*)(f + base0 + 4);
      float4 b0 = *(const float4*)(f + base1), b1 = *(const float4*)(f + base1 + 4);
      a[0]=fbf(a0.x); a[1]=fbf(a0.y); a[2]=fbf(a0.z); a[3]=fbf(a0.w);
      a[4]=fbf(a1.x); a[5]=fbf(a1.y); a[6]=fbf(a1.z); a[7]=fbf(a1.w);
      b[0]=fbf(b0.x); b[1]=fbf(b0.y); b[2]=fbf(b0.z); b[3]=fbf(b0.w);
      b[4]=fbf(b1.x); b[5]=fbf(b1.y); b[6]=fbf(b1.z); b[7]=fbf(b1.w);
    } else {
      short8v va = *(const short8v*)((const u16*)w + base0);
      short8v vb = *(const short8v*)((const u16*)w + base1);
      #pragma unroll
      for (int k = 0; k < 8; ++k){ a[k] = (u16)va[k]; b[k] = (u16)vb[k]; }
    }
    int slot = (jp >> 2) ^ pg;
    int sub  = jp & 3;
    #pragma unroll
    for (int k = 0; k < 8; ++k){
      int pp = pg*8 + k;
      tile[pp*64 + slot*4 + sub] = (u32)a[k] | ((u32)b[k] << 16);
    }
  }
  __syncthreads();
  for (int it = 0; it < 8; ++it){
    int idx = it*256 + threadIdx.x;        // [0,2048)
    int pp = idx >> 4, jb = idx & 15;
    int slot = jb ^ ((pp >> 3) & 15);
    u32x4 v = *(const u32x4*)(tile + pp*64 + slot*4);
    int p = ph*128 + pp;
    *(u32x4*)(wt + ((size_t)p*MAPD + c)*128 + jb*8) = v;
  }
}

__device__ void prep_body(bool f32, int bid, const void* c1w, const void* c2w, const void* c3w,
                          const void* fcw, const void* st0,
                          u16* W1F, u16* W2F, u16* W3F, u16* FWF, u16* ST0T, char* smem_){
  int tid = threadIdx.x;
  if (bid < 24){
    int idx = bid*256 + tid;                   // 6144
    int j = idx & 7, l = (idx>>3) & 63, t = idx>>9;
    int nt = t/6, s = t - nt*6;
    int oc = nt*16 + (l&15);
    int kk = 8*(4*s + (l>>4)) + j;
    float v = ldf(f32, c1w, oc*192+kk);
    W1F[idx] = fbf(v);
  } else if (bid < 152){
    int idx = (bid-24)*256 + tid;              // 32768
    int j = idx & 7, l = (idx>>3) & 63, s = (idx>>9) & 15, nt = idx>>13;
    int oc = nt*16 + (l&15);
    int cin = (l>>4)*8 + j;
    int src = oc*512 + cin*16 + (s>>2)*4 + (s&3);
    W2F[idx] = fbf(ldf(f32, c2w, src));
  } else if (bid < 296){
    int idx = (bid-152)*256 + tid;             // 36864
    int j = idx & 7, l = (idx>>3) & 63, t = idx>>9;   // t = nt*18+s
    int nt = t/18, s = t - nt*18;
    int oc = nt*16 + (l&15);
    int c = (s&1)*32 + (l>>4)*8 + j;
    int src = oc*576 + c*9 + (s>>1);
    W3F[idx] = fbf(ldf(f32, c3w, src));
  } else if (bid < 424){
    // FWF: MFMA B-fragments of fc_w for fc GEMM.
    int b = bid - 296;                          // 128 blocks x 4096 elems
    for (int it = 0; it < 16; ++it){
      int idx = (b*16 + it)*256 + tid;          // 524288 total
      int j = idx & 7, l = (idx>>3) & 63, frag = idx >> 9;
      int nt = frag >> 5, kt = frag & 31;
      int kc = kt*32 + ((l>>4)<<3) + j;
      int kr = (kc & 63)*16 + (kc >> 6);
      int o  = nt*16 + (l & 15);
      FWF[idx] = fbf(ldf(f32, fcw, (size_t)o*1024 + kr));
    }
  } else {
    // ST0T[p][c][b] transpose — vectorized both sides, pad-36 LDS, rotated write order.
    // Two half-tiles of 4 c's each keep LDS usage <= 18,432 B (kernel stays at 32 KB).
    u16* tile = (u16*)smem_;                   // [ci<4][pl<64] stride 36 u16 + b
    int b0 = bid - 424;                        // 260 blocks
    int c0 = (b0 >> 2)*8, p0 = (b0 & 3)*64;
    for (int half = 0; half < 2; ++half){
      int ch = c0 + half*4;
      for (int it = 0; it < 4; ++it){
        int idx = it*256 + tid;                // [0,1024)
        int pg = idx & 7, b = (idx>>3) & 31, ci = idx >> 8;   // ci 0..3
        int c = ch + ci;
        u16 v[8];
        if (c < MAPD){
          size_t src = ((size_t)b*MAPD + c)*256 + p0 + pg*8;
          if (f32){
            const float* f = (const float*)st0;
            float4 x0 = *(const float4*)(f + src), x1 = *(const float4*)(f + src + 4);
            v[0]=fbf(x0.x); v[1]=fbf(x0.y); v[2]=fbf(x0.z); v[3]=fbf(x0.w);
            v[4]=fbf(x1.x); v[5]=fbf(x1.y); v[6]=fbf(x1.z); v[7]=fbf(x1.w);
          } else {
            short8v x = *(const short8v*)((const u16*)st0 + src);
            #pragma unroll
            for (int k = 0; k < 8; ++k) v[k] = (u16)x[k];
          }
        } else {
          #pragma unroll
          for (int k = 0; k < 8; ++k) v[k] = 0;
        }
        // rotated issue order spreads banks across pg (else 8-way conflict)
        #pragma unroll
        for (int kk = 0; kk < 8; ++kk){
          int k2 = (kk + pg) & 7;
          tile[ci*2304 + (pg*8 + k2)*36 + b] = v[k2];
        }
      }
      __syncthreads();
      for (int it = 0; it < 8; ++it){
        int idx = it*256 + tid;                // [0,2048)
        int bq = idx & 7, pl = (idx>>3) & 63, ci = idx >> 9;  // ci 0..3
        int c = ch + ci;
        if (c < MAPD){
          ushort4 v = *(const ushort4*)(tile + ci*2304 + pl*36 + bq*4);
          *(ushort4*)(ST0T + ((size_t)(p0+pl)*MAPD + c)*32 + bq*4) = v;
        }
      }
      __syncthreads();
    }
  }
}

__device__ void meta_body(bool f32, int bid, const int* pos, const void* done, const int* lact,
                          int* prev, float* coef, float* H, int* lastw, float* lastc){
  if (bid < 4){
    int i = bid*256 + threadIdx.x;
    int t = i >> 5, b = i & 31;
    int p = pos[i*2]*16 + pos[i*2+1];
    int pv = -1;
    for (int s = t-1; s >= 0; --s){
      int n = s*32 + b;
      if (pos[n*2]*16 + pos[n*2+1] == p){ pv = s; break; }
    }
    float cf = 1.f;
    for (int s = (pv<0?0:pv+1); s <= t-1; ++s)
      cf *= (1.f - ldf(f32, done, s*32+b));
    prev[i] = pv; coef[i] = cf;
    int la = lact[i];
    #pragma unroll
    for (int a = 0; a < 5; ++a) H[(size_t)i*MAPD + 512 + a] = (la == a) ? 1.f : 0.f;
  } else {
    int i = (bid-4)*256 + threadIdx.x;
    int b = i >> 8, p = i & 255;
    int lw = -1;
    for (int s = T_-1; s >= 0; --s){
      int n = s*32 + b;
      if (pos[n*2]*16 + pos[n*2+1] == p){ lw = s; break; }
    }
    float cf = 1.f;
    for (int s = (lw<0?0:lw+1); s < T_; ++s)
      cf *= (1.f - ldf(f32, done, s*32+b));
    lastw[i] = lw; lastc[i] = cf;
  }
}

__global__ __launch_bounds__(256) void k_A(const void* image,
                                           const void* pw1, const void* vw1, u16* wt,
                                           const void* c1w, const void* c2w, const void* c3w,
                                           const void* fcw, const void* st0,
                                           u16* W1F, u16* W2F, u16* W3F, u16* FWF, u16* ST0T,
                                           const int* pos, const void* done, const int* lact,
                                           int* prev, float* coef, float* H, int* lastw, float* lastc){
  __shared__ __align__(16) char smem_[32768];
  bool f32 = probe_f32(image);
  int bid = blockIdx.x;
  if (bid < 1034){
    if (f32) wt_body<true>(bid, pw1, vw1, wt, (u32*)smem_);
    else     wt_body<false>(bid, pw1, vw1, wt, (u32*)smem_);
  } else if (bid < 1718){
    prep_body(f32, bid-1034, c1w, c2w, c3w, fcw, st0, W1F, W2F, W3F, FWF, ST0T, smem_);
  } else {
    meta_body(f32, bid-1718, pos, done, lact, prev, coef, H, lastw, lastc);
  }
}

// ================= k_conv123: fused convs =================
__global__ __launch_bounds__(256) void k_conv123(const void* img,
                                                 const u16* __restrict__ W1F, const void* b1,
                                                 const u16* __restrict__ W2F, const void* b2,
                                                 const u16* __restrict__ W3F, const void* b3,
                                                 u16* __restrict__ out){
  __shared__ __align__(16) u16 smem[19488];
  u16* sImg = smem;            // 12288 u16
  u16* sA   = smem + 12288;    // 7200 u16
  u16* sBv  = smem;            // 2304 u16, overlays sImg after conv1
  bool f32 = probe_f32(img);
  int n = blockIdx.x, tid = threadIdx.x;
  if (f32){
    const float4* ip = (const float4*)((const float*)img + (size_t)n*12288);
    for (int i = tid; i < 3072; i += 256){
      float4 v = ip[i];
      ushort4 u; u.x = fbf(v.x); u.y = fbf(v.y); u.z = fbf(v.z); u.w = fbf(v.w);
      int L = i*4;
      int addr = (L & ~63) | (((L & 63) + (((L >> 6) & 3) << 4)) & 63);
      *(ushort4*)(sImg + addr) = u;
    }
  } else {
    const ushort4* ip = (const ushort4*)((const u16*)img + (size_t)n*12288);
    for (int i = tid; i < 3072; i += 256){
      ushort4 u = ip[i];
      int L = i*4;
      int addr = (L & ~63) | (((L & 63) + (((L >> 6) & 3) << 4)) & 63);
      *(ushort4*)(sImg + addr) = u;
    }
  }
  int wv = tid >> 6, lane = tid & 63;
  int mi = lane & 15, q = lane >> 4;

  short8v bfr1[2][6];
  #pragma unroll
  for (int nt = 0; nt < 2; ++nt)
    #pragma unroll
    for (int s = 0; s < 6; ++s)
      bfr1[nt][s] = ((const short8v*)W1F)[(nt*6+s)*64 + lane];
  float b1v[2];
  #pragma unroll
  for (int nt = 0; nt < 2; ++nt)
    b1v[nt] = ldf(f32, b1, nt*16+mi);
  __syncthreads();

  {
    f32x4 acc[4][2];
    #pragma unroll
    for (int mt = 0; mt < 4; ++mt)
      #pragma unroll
      for (int nt = 0; nt < 2; ++nt)
        acc[mt][nt] = (f32x4){0.f,0.f,0.f,0.f};
    int base[4];
    #pragma unroll
    for (int mt = 0; mt < 4; ++mt){
      int m = (wv*4+mt)*16 + mi;
      int mc = m < 225 ? m : 224;
      int oy = mc/15, ox = mc - oy*15;
      base[mt] = oy*256 + ox*4;
    }
    for (int s = 0; s < 6; ++s){
      int cky = 4*s + q;
      int off = (cky >> 3)*4096 + (cky & 7)*64;
      #pragma unroll
      for (int mt = 0; mt < 4; ++mt){
        int Lb = base[mt] + off;
        const u16* rp = sImg + (Lb & ~63);
        int x0 = Lb & 63;
        int rot = ((Lb >> 6) & 3) << 4;
        short4v lo = *(const short4v*)(rp + ((x0 + rot) & 63));
        short4v hi = *(const short4v*)(rp + ((x0 + 4 + rot) & 63));
        short8v a = __builtin_shufflevector(lo, hi, 0,1,2,3,4,5,6,7);
        acc[mt][0] = __builtin_amdgcn_mfma_f32_16x16x32_bf16(a, bfr1[0][s], acc[mt][0], 0,0,0);
        acc[mt][1] = __builtin_amdgcn_mfma_f32_16x16x32_bf16(a, bfr1[1][s], acc[mt][1], 0,0,0);
      }
    }
    __syncthreads();   // sImg reads done before sBv (alias) writes in conv2
    #pragma unroll
    for (int mt = 0; mt < 4; ++mt){
      int mrow0 = (wv*4+mt)*16 + q*4;
      #pragma unroll
      for (int nt = 0; nt < 2; ++nt){
        int oc = nt*16 + mi;
        #pragma unroll
        for (int r = 0; r < 4; ++r){
          int m = mrow0 + r;
          if (m < 225){
            int g = ((oc >> 3) ^ ((m >> 1) & 3)) << 3;
            sA[m*32 + g + (oc & 7)] = fbf(fmaxf(acc[mt][nt][r] + b1v[nt], 0.f));
          }
        }
      }
    }
  }
  __syncthreads();

  {
    short8v bfr2[16];
    #pragma unroll
    for (int s = 0; s < 16; ++s)
      bfr2[s] = ((const short8v*)W2F)[(wv*16+s)*64 + lane];
    int oc = wv*16 + mi;
    float bv = ldf(f32, b2, oc);
    f32x4 acc[3];
    #pragma unroll
    for (int mt = 0; mt < 3; ++mt) acc[mt] = (f32x4){0.f,0.f,0.f,0.f};
    int pixb[3];
    #pragma unroll
    for (int mt = 0; mt < 3; ++mt){
      int m = mt*16 + mi; if (m > 35) m = 35;
      int oy = m/6, ox = m - oy*6;
      pixb[mt] = oy*30 + ox*2;
    }
    #pragma unroll
    for (int s = 0; s < 16; ++s){
      int dp = (s>>2)*15 + (s&3);
      #pragma unroll
      for (int mt = 0; mt < 3; ++mt){
        int pix = pixb[mt] + dp;
        int g = (q ^ ((pix >> 1) & 3)) << 3;
        short8v a = *(const short8v*)(sA + pix*32 + g);
        acc[mt] = __builtin_amdgcn_mfma_f32_16x16x32_bf16(a, bfr2[s], acc[mt], 0,0,0);
      }
    }
    __syncthreads();
    #pragma unroll
    for (int mt = 0; mt < 3; ++mt)
      #pragma unroll
      for (int r = 0; r < 4; ++r){
        int m = mt*16 + q*4 + r;
        if (m < 36){
          int g = ((oc >> 3) ^ (m & 7)) << 3;
          sBv[m*64 + g + (oc & 7)] = fbf(fmaxf(acc[mt][r] + bv, 0.f));
        }
      }
  }
  __syncthreads();

  {
    int oy = mi >> 2, ox = mi & 3;
    int oc = wv*16 + mi;
    float bv = ldf(f32, b3, oc);
    short8v bfr3[18];
    #pragma unroll
    for (int s = 0; s < 18; ++s)
      bfr3[s] = ((const short8v*)W3F)[(wv*18+s)*64 + lane];
    f32x4 acc = (f32x4){0.f,0.f,0.f,0.f};
    #pragma unroll
    for (int s = 0; s < 18; ++s){
      int pair = s >> 1, ky = pair/3, kx = pair - ky*3;
      int pix = (oy+ky)*6 + ox+kx;
      int g = ((((s & 1) << 2) | q) ^ (pix & 7)) << 3;
      short8v a = *(const short8v*)(sBv + pix*64 + g);
      acc = __builtin_amdgcn_mfma_f32_16x16x32_bf16(a, bfr3[s], acc, 0,0,0);
    }
    u16* ob = out + (size_t)n*1024;
    #pragma unroll
    for (int r = 0; r < 4; ++r)
      ob[(q*4+r)*64 + oc] = fbf(fmaxf(acc[r] + bv, 0.f));
  }
}

// ================= k_C: yinit (1024) + fc (512) =================
template<int CLEN>
__device__ __forceinline__ void yloop(const u16* __restrict__ wp, const float* __restrict__ sSb,
                                      float (&acc)[8][2]){
  #pragma unroll 10
  for (int c = 0; c < CLEN; ++c){
    u32 w = *(const u32*)(wp + (size_t)c*128);
    float w0 = bfv((u16)(w & 0xffffu)), w1 = bfv((u16)(w >> 16));
    const float4* s4 = (const float4*)(sSb + c*32);
    float4 sa = s4[0], sb = s4[1];
    float sv[8] = {sa.x,sa.y,sa.z,sa.w,sb.x,sb.y,sb.z,sb.w};
    #pragma unroll
    for (int bb = 0; bb < 8; ++bb){
      acc[bb][0] += sv[bb]*w0;
      acc[bb][1] += sv[bb]*w1;
    }
  }
}
__device__ void yinit_body(int lbid, const u16* __restrict__ ST0T, const u16* __restrict__ wt,
                           u16* __restrict__ PARTB, float* sS){
  int p = lbid >> 2, cq = lbid & 3;
  int c0 = cq*130;
  int clen = (cq == 3) ? 127 : 130;
  const ushort4* ssrc = (const ushort4*)(ST0T + ((size_t)p*MAPD + c0)*32);
  int n4 = clen*8;
  for (int i = threadIdx.x; i < n4; i += 256){
    ushort4 u = ssrc[i];
    float4 f; f.x = bfv(u.x); f.y = bfv(u.y); f.z = bfv(u.z); f.w = bfv(u.w);
    *(float4*)(sS + i*4) = f;
  }
  __syncthreads();
  int jg = threadIdx.x & 63, bg = threadIdx.x >> 6;
  int j0 = jg*2, b0 = bg*8;
  const u16* wp = wt + ((size_t)p*MAPD + c0)*128 + j0;
  float acc[8][2] = {};
  if (cq < 3) yloop<130>(wp, sS + b0, acc);
  else        yloop<127>(wp, sS + b0, acc);
  u32* op = (u32*)(PARTB + (size_t)lbid*4096);
  #pragma unroll
  for (int bb = 0; bb < 8; ++bb){
    u32 pk = (u32)fbf(acc[bb][0]) | ((u32)fbf(acc[bb][1]) << 16);
    op[((b0+bb)*128 + j0) >> 1] = pk;
  }
}
__device__ void fc_body(int lbid, bool f32, const u16* __restrict__ C, const u16* __restrict__ FWF,
                        const void* fb, float* __restrict__ H){
  int wv = threadIdx.x >> 6, lane = threadIdx.x & 63;
  int mi = lane & 15, q = lane >> 4;
  int mt = lbid >> 3;               // 0..63
  int nt = (lbid & 7)*4 + wv;       // 0..31
  const u16* ap = C + (size_t)(mt*16 + mi)*1024 + q*8;
  const short8v* bp = (const short8v*)FWF + (size_t)nt*32*64 + lane;
  f32x4 acc0 = (f32x4){0.f,0.f,0.f,0.f};
  f32x4 acc1 = (f32x4){0.f,0.f,0.f,0.f};
  #pragma unroll
  for (int kt = 0; kt < 32; kt += 2){
    short8v a0 = *(const short8v*)(ap + kt*32);
    short8v b0 = bp[kt*64];
    short8v a1 = *(const short8v*)(ap + (kt+1)*32);
    short8v b1 = bp[(kt+1)*64];
    acc0 = __builtin_amdgcn_mfma_f32_16x16x32_bf16(a0, b0, acc0, 0,0,0);
    acc1 = __builtin_amdgcn_mfma_f32_16x16x32_bf16(a1, b1, acc1, 0,0,0);
  }
  int o = nt*16 + mi;
  float bv = ldf(f32, fb, o);
  #pragma unroll
  for (int r = 0; r < 4; ++r){
    int m = mt*16 + q*4 + r;
    H[(size_t)m*MAPD + o] = fmaxf(acc0[r] + acc1[r] + bv, 0.f);
  }
}
__global__ __launch_bounds__(256) void k_C(const void* image,
                                           const u16* __restrict__ ST0T, const u16* __restrict__ wt,
                                           u16* __restrict__ PARTB,
                                           const u16* __restrict__ C, const u16* __restrict__ FWF,
                                           const void* fb, float* __restrict__ H){
  __shared__ float sS[130*32];   // 16.6 KB (yinit branch)
  if (blockIdx.x < 1024){
    yinit_body(blockIdx.x, ST0T, wt, PARTB, sS);
  } else {
    bool f32 = probe_f32(image);
    fc_body(blockIdx.x - 1024, f32, C, FWF, fb, H);
  }
}

// ================= k_D: delta (2048 blocks x 2 units) + yred (64) =================
__device__ void delta_body(int obid, int ltid, float* diff, bool f32,
                           const float* __restrict__ H, const u16* __restrict__ wt,
                           const u16* __restrict__ st0t,
                           const int* __restrict__ pos, const void* done,
                           const int* __restrict__ prev, const float* __restrict__ coef,
                           float* __restrict__ dlt8){
  int n = obid >> 2, cq = obid & 3;
  int c0 = cq*130, clen = (cq == 3) ? 127 : 130;
  int b = n & 31;
  int p = pos[n*2]*16 + pos[n*2+1];
  float dn = ldf(f32, done, n);
  float m = 1.f - dn;
  int pv = prev[n];
  float cf = coef[n]*m;
  const float* hc = H + (size_t)n*MAPD + c0;
  for (int c = ltid; c < clen; c += 128){
    float old;
    if (pv >= 0) old = H[(size_t)(pv*32 + b)*MAPD + c0 + c];
    else         old = bfv(st0t[((size_t)p*MAPD + c0 + c)*32 + b]);
    diff[c] = hc[c] - cf*old;
  }
  __syncthreads();
  int half = ltid >> 6, jp = ltid & 63, j0 = jp*2;
  int hbase, hlen;
  if (cq == 3){ hbase = half*64; hlen = half ? 63 : 64; }
  else        { hbase = half*65; hlen = 65; }
  const u16* wp = wt + ((size_t)p*MAPD + c0 + hbase)*128 + j0;
  const float* dptr = diff + hbase;
  float a0 = 0.f, a1 = 0.f;
  int c = 0;
  for (; c + 4 <= hlen; c += 4){
    u32 w0 = *(const u32*)(wp + (size_t)(c+0)*128);
    u32 w1 = *(const u32*)(wp + (size_t)(c+1)*128);
    u32 w2 = *(const u32*)(wp + (size_t)(c+2)*128);
    u32 w3 = *(const u32*)(wp + (size_t)(c+3)*128);
    float d0 = dptr[c], d1 = dptr[c+1], d2 = dptr[c+2], d3 = dptr[c+3];
    a0 += d0*bfv((u16)(w0 & 0xffffu)) + d1*bfv((u16)(w1 & 0xffffu))
        + d2*bfv((u16)(w2 & 0xffffu)) + d3*bfv((u16)(w3 & 0xffffu));
    a1 += d0*bfv((u16)(w0 >> 16)) + d1*bfv((u16)(w1 >> 16))
        + d2*bfv((u16)(w2 >> 16)) + d3*bfv((u16)(w3 >> 16));
  }
  for (; c < hlen; ++c){
    u32 w = *(const u32*)(wp + (size_t)c*128);
    a0 += dptr[c]*bfv((u16)(w & 0xffffu));
    a1 += dptr[c]*bfv((u16)(w >> 16));
  }
  f32x2 st; st[0] = a0; st[1] = a1;
  *(f32x2*)(dlt8 + ((size_t)obid*2 + half)*128 + j0) = st;
}
__global__ __launch_bounds__(256) void k_D(const void* image,
                                           const float* __restrict__ H, const u16* __restrict__ wt,
                                           const u16* __restrict__ st0t,
                                           const int* __restrict__ pos, const void* done,
                                           const int* __restrict__ prev, const float* __restrict__ coef,
                                           float* __restrict__ dlt8,
                                           const u16* __restrict__ PARTB, float* __restrict__ YI){
  __shared__ float diff2[2][132];
  __shared__ float red[256];
  if (blockIdx.x < 2048){
    bool f32 = probe_f32(image);
    int sub = threadIdx.x >> 7;
    int obid = blockIdx.x*2 + sub;
    delta_body(obid, threadIdx.x & 127, diff2[sub], f32, H, wt, st0t, pos, done, prev, coef, dlt8);
  } else {
    int lbid = blockIdx.x - 2048;
    int o = lbid*64 + (threadIdx.x & 63);
    int kq = threadIdx.x >> 6;
    float s = 0.f;
    const u16* pp = PARTB + (size_t)kq*256*4096 + o;
    #pragma unroll 8
    for (int k = 0; k < 256; ++k) s += bfv(pp[(size_t)k*4096]);
    red[threadIdx.x] = s;
    __syncthreads();
    if (threadIdx.x < 64)
      YI[o] = red[threadIdx.x] + red[threadIdx.x+64] + red[threadIdx.x+128] + red[threadIdx.x+192];
  }
}

// ================= k_E: scan+heads (32) + final (16544) =================
__device__ void scan_heads_body(bool f32, const float* __restrict__ yi,
                                const float* __restrict__ dlt8, const void* done,
                                const void* pb1, const void* vb1,
                                const void* pw2, const void* pb2,
                                const void* vw2, const void* vb2, void* out){
  int b = blockIdx.x, j = threadIdx.x;       // j in [0,128)
  int lane = j & 63;
  bool pol = j < 64;
  float y = yi[b*128 + j];
  float bias = pol ? ldf(f32, pb1, j) : ldf(f32, vb1, j-64);
  float w2[5];
  if (pol){
    #pragma unroll
    for (int jj = 0; jj < 5; ++jj) w2[jj] = ldf(f32, pw2, jj*64 + lane);
  } else {
    w2[0] = ldf(f32, vw2, lane);
  }
  for (int t = 0; t < T_; ++t){
    int n = t*32 + b;
    float m = 1.f - ldf(f32, done, n);
    const float* dp = dlt8 + (size_t)n*1024 + j;
    float d = dp[0] + dp[128] + dp[256] + dp[384]
            + dp[512] + dp[640] + dp[768] + dp[896];
    y = m*y + d;
    float th = tanhf(y + bias);
    if (pol){
      float s0 = th*w2[0], s1 = th*w2[1], s2 = th*w2[2], s3 = th*w2[3], s4 = th*w2[4];
      #pragma unroll
      for (int off = 32; off > 0; off >>= 1){
        s0 += __shfl_xor(s0, off, 64);
        s1 += __shfl_xor(s1, off, 64);
        s2 += __shfl_xor(s2, off, 64);
        s3 += __shfl_xor(s3, off, 64);
        s4 += __shfl_xor(s4, off, 64);
      }
      if (lane == 0){
        float sv[5] = {s0,s1,s2,s3,s4};
        #pragma unroll
        for (int jj = 0; jj < 5; ++jj){
          float s = sv[jj] + ldf(f32, pb2, jj);
          if (f32) ((float*)out)[n*5 + jj] = s; else ((u16*)out)[n*5 + jj] = fbf(s);
        }
      }
    } else {
      float s = th*w2[0];
      #pragma unroll
      for (int off = 32; off > 0; off >>= 1) s += __shfl_xor(s, off, 64);
      if (lane == 0){
        s += ldf(f32, vb2, 0);
        if (f32) ((float*)out)[5120 + n] = s; else ((u16*)out)[5120 + n] = fbf(s);
      }
    }
  }
}
__global__ __launch_bounds__(256) void k_E(const void* image,
                                           const float* __restrict__ yi, const float* __restrict__ dlt8,
                                           const void* done, const void* pb1, const void* vb1,
                                           const void* pw2, const void* pb2,
                                           const void* vw2, const void* vb2,
                                           const float* __restrict__ H, const void* st0,
                                           const int* __restrict__ lastw, const float* __restrict__ lastc,
                                           void* out){
  bool f32 = probe_f32(image);
  if (blockIdx.x < 32){
    if (threadIdx.x >= 128) return;
    scan_heads_body(f32, yi, dlt8, done, pb1, vb1, pw2, pb2, vw2, vb2, out);
  } else {
    size_t i = (size_t)(blockIdx.x - 32)*256 + threadIdx.x;
    if (i >= (size_t)B_*FLATD) return;
    int b = (int)(i / FLATD);
    int r = (int)(i - (size_t)b*FLATD);
    int c = r >> 8, p = r & 255;
    int lw = lastw[b*256 + p];
    float lc = lastc[b*256 + p];
    float v;
    if (lw >= 0) v = H[(size_t)(lw*32 + b)*MAPD + c]*lc;
    else         v = ldf(f32, st0, i)*lc;
    if (f32) ((float*)out)[6144 + i] = v; else ((u16*)out)[6144 + i] = fbf(v);
  }
}

extern "C" void kernel_launch(void* const* d_in, const int* in_sizes, int n_in,
                              void* d_out, int out_size, void* d_ws, size_t ws_size,
                              hipStream_t stream) {
  (void)in_sizes; (void)n_in; (void)out_size; (void)ws_size;
  const void* image = d_in[0];
  const int*  lact  = (const int*)d_in[1];
  const int*  pos   = (const int*)d_in[2];
  const void* done  = d_in[3];
  const void* st0   = d_in[4];
  const void* c1w = d_in[5];  const void* c1b = d_in[6];
  const void* c2w = d_in[7];  const void* c2b = d_in[8];
  const void* c3w = d_in[9];  const void* c3b = d_in[10];
  const void* fcw = d_in[11]; const void* fcb = d_in[12];
  const void* pw1 = d_in[13]; const void* pb1 = d_in[14];
  const void* pw2 = d_in[15]; const void* pb2 = d_in[16];
  const void* vw1 = d_in[17]; const void* vb1 = d_in[18];
  const void* vw2 = d_in[19]; const void* vb2 = d_in[20];
  char* ws = (char*)d_ws;

  // workspace (~60.5 MB). No live overlays.
  u16*   WT    = (u16*)  (ws + 0);           // 33,882,112
  float* H     = (float*)(ws + 33882368);    // 2,117,632
  float* YI    = (float*)(ws + 36000256);    // 16,384
  u16*   PARTB = (u16*)  (ws + 36016640);    // 8,388,608
  int*   PREV  = (int*)  (ws + 44405248);
  float* COEF  = (float*)(ws + 44409344);
  int*   LASTW = (int*)  (ws + 44413440);
  float* LASTC = (float*)(ws + 44446208);
  u16*   W1F   = (u16*)  (ws + 44479232);    // 12,288
  u16*   W2F   = (u16*)  (ws + 44491520);    // 65,536
  u16*   W3F   = (u16*)  (ws + 44557056);    // 73,728
  u16*   FWF   = (u16*)  (ws + 44630784);    // 1,048,576
  u16*   ST0T  = (u16*)  (ws + 45679360);    // 8,470,528 -> 54,149,888
  u16*   C     = (u16*)  (ws + 54149888);    // 2,097,152 -> 56,247,040
  float* DLT8  = (float*)(ws + 56247040);    // 4,194,304 -> 60,441,344

  k_A      <<<1754, 256, 0, stream>>>(image, pw1, vw1, WT, c1w, c2w, c3w, fcw, st0,
                                      W1F, W2F, W3F, FWF, ST0T,
                                      pos, done, lact, PREV, COEF, H, LASTW, LASTC);
  k_conv123<<<1024, 256, 0, stream>>>(image, W1F, c1b, W2F, c2b, W3F, c3b, C);
  k_C      <<<1536, 256, 0, stream>>>(image, ST0T, WT, PARTB, C, FWF, fcb, H);
  k_D      <<<2112, 256, 0, stream>>>(image, H, WT, ST0T, pos, done, PREV, COEF, DLT8, PARTB, YI);
  k_E      <<<16576, 256, 0, stream>>>(image, YI, DLT8, done, pb1, vb1, pw2, pb2, vw2, vb2,
                                       H, st0, LASTW, LASTC, d_out);
}